// Round 1
// 2512.706 us; speedup vs baseline: 1.0009x; 1.0009x over previous
//
#include <hip/hip_runtime.h>
#include <math.h>

// Problem constants
#define B_SZ    4096
#define D_DIM   128
#define K_CODES 8192
#define RECON_N (4096*84*84)   // 28901376

// ============================ VQ argmin + losses ============================
// Exact numpy-f32 semantics (verified R2/R3): d2q = fl32(zz - 2r), r = sequential
// f32 FMA chain over d ascending, zz = numpy pairwise-8. Ties -> lowest index.
// R4: 256 blocks x 1024 threads (16 waves/CU vs R3's 4) — R3 was latency-bound
// at 1 wave/SIMD. Waves partition the 128 code-groups; cb read as float4 from
// global (L2-resident, 64B lines consumed immediately); z broadcast from LDS.
__global__ __attribute__((amdgpu_flat_work_group_size(1024,1024),
                          amdgpu_waves_per_eu(4,8)))
void vq_kernel(
    const float* __restrict__ z, const float* __restrict__ cb,
    int* __restrict__ idx_ws, float* __restrict__ out_idx_f,
    double* __restrict__ lpart)
{
  __shared__ float z_s[16][128];
  __shared__ float zz_s[16];
  __shared__ float redv[16][16];   // [wave][row]
  __shared__ int   redi[16][16];
  __shared__ int   win[16];
  __shared__ double wsum[16];
  const int t  = threadIdx.x;
  const int b0 = blockIdx.x * 16;

  for (int p = t; p < 2048; p += 1024) z_s[p >> 7][p & 127] = z[(size_t)b0*128 + p];
  __syncthreads();

  // numpy pairwise-8 emulation of (z*z).sum(axis=1); separate mul/add roundings
  if (t < 16) {
    #pragma clang fp contract(off)
    const float* a = z_s[t];
    float r8[8];
    #pragma unroll
    for (int j = 0; j < 8; j++) { float v = a[j]*a[j]; r8[j] = v; }
    for (int i = 8; i < 128; i += 8) {
      #pragma unroll
      for (int j = 0; j < 8; j++) { float v = a[i+j]*a[i+j]; r8[j] = r8[j] + v; }
    }
    zz_s[t] = ((r8[0]+r8[1]) + (r8[2]+r8[3])) + ((r8[4]+r8[5]) + (r8[6]+r8[7]));
  }
  __syncthreads();

  const int lane = t & 63, wv = t >> 6;
  float zzr[16];
  #pragma unroll
  for (int row = 0; row < 16; row++) zzr[row] = zz_s[row];

  float best[16]; int bid[16];
  #pragma unroll
  for (int row = 0; row < 16; row++) { best[row] = INFINITY; bid[row] = 0; }

  #pragma unroll 1
  for (int k = 0; k < 8; k++) {
    const int cg   = wv + (k << 4);        // 16 waves cover 128 groups of 64 codes
    const int code = (cg << 6) + lane;     // ascending in k for fixed lane
    const float* ep = cb + (size_t)code * 128;
    float r[16];
    #pragma unroll
    for (int row = 0; row < 16; row++) r[row] = 0.0f;
    #pragma unroll 1
    for (int d16 = 0; d16 < 8; d16++) {
      const float4 e0 = *(const float4*)(ep + d16*16 + 0);
      const float4 e1 = *(const float4*)(ep + d16*16 + 4);
      const float4 e2 = *(const float4*)(ep + d16*16 + 8);
      const float4 e3 = *(const float4*)(ep + d16*16 + 12);
      #pragma unroll
      for (int row = 0; row < 16; row++) {
        const float4 z0 = *(const float4*)(&z_s[row][d16*16 + 0]);   // uniform -> broadcast
        const float4 z1 = *(const float4*)(&z_s[row][d16*16 + 4]);
        const float4 z2 = *(const float4*)(&z_s[row][d16*16 + 8]);
        const float4 z3 = *(const float4*)(&z_s[row][d16*16 + 12]);
        float rr = r[row];
        // single dependent FMA chain, d ascending — identical to R3 (bit-exact)
        rr = fmaf(z0.x,e0.x,rr); rr = fmaf(z0.y,e0.y,rr); rr = fmaf(z0.z,e0.z,rr); rr = fmaf(z0.w,e0.w,rr);
        rr = fmaf(z1.x,e1.x,rr); rr = fmaf(z1.y,e1.y,rr); rr = fmaf(z1.z,e1.z,rr); rr = fmaf(z1.w,e1.w,rr);
        rr = fmaf(z2.x,e2.x,rr); rr = fmaf(z2.y,e2.y,rr); rr = fmaf(z2.z,e2.z,rr); rr = fmaf(z2.w,e2.w,rr);
        rr = fmaf(z3.x,e3.x,rr); rr = fmaf(z3.y,e3.y,rr); rr = fmaf(z3.z,e3.z,rr); rr = fmaf(z3.w,e3.w,rr);
        r[row] = rr;
      }
    }
    #pragma unroll
    for (int row = 0; row < 16; row++) {
      const float tt = fmaf(-2.0f, r[row], zzr[row]);  // fl32(zz - 2r), single rounding
      if (tt < best[row]) { best[row] = tt; bid[row] = code; }
    }
  }

  // cross-lane lex argmin per row (tie -> smaller index)
  #pragma unroll 1
  for (int row = 0; row < 16; row++) {
    float v = best[row]; int i = bid[row];
    #pragma unroll
    for (int m = 32; m; m >>= 1) {
      float v2 = __shfl_xor(v, m, 64);
      int   i2 = __shfl_xor(i, m, 64);
      if (v2 < v || (v2 == v && i2 < i)) { v = v2; i = i2; }
    }
    if (lane == 0) { redv[wv][row] = v; redi[wv][row] = i; }
  }
  __syncthreads();

  if (t < 16) {   // row t: reduce over 16 waves
    float v = redv[0][t]; int i = redi[0][t];
    #pragma unroll 1
    for (int w = 1; w < 16; w++) {
      float v2 = redv[w][t]; int i2 = redi[w][t];
      if (v2 < v || (v2 == v && i2 < i)) { v = v2; i = i2; }
    }
    win[t] = i;
    idx_ws[b0 + t] = i;
    out_idx_f[b0 + t] = (float)i;   // float out; exact for idx < 2^24
  }
  __syncthreads();

  // loss partial: sum (z - e_win)^2 over 16 rows (f64; threshold slack huge)
  double ls = 0.0;
  for (int p = t; p < 2048; p += 1024) {
    int r = p >> 7, d = p & 127;
    float diff = z_s[r][d] - cb[(size_t)win[r]*128 + d];
    ls = fma((double)diff, (double)diff, ls);
  }
  #pragma unroll
  for (int m = 32; m; m >>= 1) ls += __shfl_xor(ls, m, 64);
  if (lane == 0) wsum[wv] = ls;
  __syncthreads();
  if (t == 0) {
    double s = 0.0;
    for (int w = 0; w < 16; w++) s += wsum[w];
    lpart[blockIdx.x] = s;
  }
}

__global__ __launch_bounds__(256) void fin_kernel(const double* __restrict__ lpart,
                                                  float* __restrict__ out_loss)
{
  __shared__ double s[256];
  const int t = threadIdx.x;
  s[t] = lpart[t];
  __syncthreads();
  for (int off = 128; off; off >>= 1) {
    if (t < off) s[t] += s[t + off];
    __syncthreads();
  }
  if (t == 0) {
    float l = (float)(s[0] / (4096.0*128.0));
    out_loss[0] = l;   // codebook_loss
    out_loss[1] = l;   // commitment_loss (same value)
  }
}

// ===================== linear: x1[b,o] = cb[idx[b]] . lin_w[o] + lin_b[o] ====
__global__ __launch_bounds__(256) void linear_kernel(
    const float* __restrict__ cb, const int* __restrict__ idx,
    const float* __restrict__ lw, const float* __restrict__ lb,
    float* __restrict__ x1)
{
  __shared__ float As[64][65];
  __shared__ float Bs[64][65];
  __shared__ int idx_s[64];
  const int t  = threadIdx.x;
  const int b0 = blockIdx.x * 64, n0 = blockIdx.y * 64;
  if (t < 64) idx_s[t] = idx[b0 + t];
  float acc[4][4] = {{0.f}};
  const int tr = (t >> 4)*4, tc = (t & 15)*4;
  for (int d0 = 0; d0 < 128; d0 += 64) {
    __syncthreads();
    #pragma unroll
    for (int l = 0; l < 16; l++) {
      int flat = t + l*256;
      int r = flat >> 6, d = flat & 63;
      As[r][d] = cb[(size_t)idx_s[r]*128 + d0 + d];
      Bs[r][d] = lw[(size_t)(n0 + r)*128 + d0 + d];
    }
    __syncthreads();
    #pragma unroll 8
    for (int d = 0; d < 64; d++) {
      float a0 = As[tr+0][d], a1 = As[tr+1][d], a2 = As[tr+2][d], a3 = As[tr+3][d];
      float q0 = Bs[tc+0][d], q1 = Bs[tc+1][d], q2 = Bs[tc+2][d], q3 = Bs[tc+3][d];
      acc[0][0] = fmaf(a0,q0,acc[0][0]); acc[0][1] = fmaf(a0,q1,acc[0][1]);
      acc[0][2] = fmaf(a0,q2,acc[0][2]); acc[0][3] = fmaf(a0,q3,acc[0][3]);
      acc[1][0] = fmaf(a1,q0,acc[1][0]); acc[1][1] = fmaf(a1,q1,acc[1][1]);
      acc[1][2] = fmaf(a1,q2,acc[1][2]); acc[1][3] = fmaf(a1,q3,acc[1][3]);
      acc[2][0] = fmaf(a2,q0,acc[2][0]); acc[2][1] = fmaf(a2,q1,acc[2][1]);
      acc[2][2] = fmaf(a2,q2,acc[2][2]); acc[2][3] = fmaf(a2,q3,acc[2][3]);
      acc[3][0] = fmaf(a3,q0,acc[3][0]); acc[3][1] = fmaf(a3,q1,acc[3][1]);
      acc[3][2] = fmaf(a3,q2,acc[3][2]); acc[3][3] = fmaf(a3,q3,acc[3][3]);
    }
  }
  #pragma unroll
  for (int i = 0; i < 4; i++)
    #pragma unroll
    for (int j = 0; j < 4; j++)
      x1[(size_t)(b0 + tr + i)*3136 + n0 + tc + j] = acc[i][j] + lb[n0 + tc + j];
}

// ===================== decoder_a: conv1 + conv2 per image ====================
// R1 (this session): B1_CS 260 -> 256 so LDS = exactly 64 KiB. Counters showed
// OccupancyPercent 42% == 14 waves == ONE 896-thread block/CU; theory: the
// 66560B (>64KiB) allocation blocked 2-block co-residency. At 65536B, 2 blocks
// need 128KiB <= 160KiB. Write-conflict fallout of %32==0 stride handled by
// vectorizing the conv1 epilogue to 4x ds_write_b128 (writing halo cols 0/15
// inline), so the zero-fill shrinks to rows 0/15 only. conv2 reads are
// wave-uniform broadcasts -> conflict-free at any stride; all float4 LDS
// alignments preserved (plane stride 1024B, row stride 64B).
#define DA_T 896
#define B1_CS 256   // channel stride: 64KiB total; epilogue uses b128 writes
__global__ __attribute__((amdgpu_flat_work_group_size(DA_T, DA_T),
                          amdgpu_waves_per_eu(7, 8)))
void decoder_a(
    const float* __restrict__ x1,
    const float* __restrict__ w1, const float* __restrict__ b1,
    const float* __restrict__ w2, const float* __restrict__ b2,
    float* __restrict__ a2, int b_off)
{
  extern __shared__ float B1s[];   // 64*256 = 16384 floats = 64 KiB
  const int tid = threadIdx.x;
  const int b   = blockIdx.x;        // local index into a2 chunk buffer
  const int bg  = b + b_off;         // global image index

  // zero only halo rows 0 and 15 of each channel plane (interior rows incl.
  // halo cols 0/15 are fully written by the conv1 epilogue below)
  for (int p = tid; p < 64*2*16; p += DA_T) {
    const int c   = p >> 5;
    const int row = ((p >> 4) & 1) * 15;
    const int col = p & 15;
    B1s[c*B1_CS + row*16 + col] = 0.0f;
  }
  __syncthreads();

  // ---- conv1: (64,7,7) -> (64,14,14), relu. item = (c=tid&63, y=tid>>6) ----
  {
    const int c = tid & 63, y = tid >> 6;
    const int ky0 = (y & 1) ? 0 : 1;
    const int iy0 = (y + 1 - ky0) >> 1;   // valid if <7
    const int iy1 = iy0 - 1;              // valid if >=0
    const bool v0 = (iy0 < 7), v1 = (iy1 >= 0);   // wave-uniform (y = wave idx)
    float acc[14];
    const float bias = b1[c];
    #pragma unroll
    for (int x = 0; x < 14; x++) acc[x] = bias;
    const float* xim = x1 + (size_t)bg*3136;
    #pragma unroll 1
    for (int i = 0; i < 64; i++) {
      const float* wp = w1 + (((i << 6) + c) << 4) + ky0*4;
      const float4 wA4 = *(const float4*)(wp);
      const float4 wB4 = *(const float4*)(wp + 8);
      const float wa[4] = {wA4.x, wA4.y, wA4.z, wA4.w};
      const float wb[4] = {wB4.x, wB4.y, wB4.z, wB4.w};
      float r0[7], r1[7];
      if (v0) {
        const float* xr = xim + i*49 + iy0*7;
        #pragma unroll
        for (int j = 0; j < 7; j++) r0[j] = xr[j];
      } else {
        #pragma unroll
        for (int j = 0; j < 7; j++) r0[j] = 0.0f;
      }
      if (v1) {
        const float* xr = xim + i*49 + iy1*7;
        #pragma unroll
        for (int j = 0; j < 7; j++) r1[j] = xr[j];
      } else {
        #pragma unroll
        for (int j = 0; j < 7; j++) r1[j] = 0.0f;
      }
      #pragma unroll
      for (int x = 0; x < 14; x++) {
        const int kxs = (x & 1) ? 0 : 1;
        const int ix0 = (x + 1 - kxs) >> 1;
        const int ix1 = ix0 - 1;
        float s = acc[x];
        if (ix0 < 7)  { s = fmaf(r0[ix0], wa[kxs],   s); s = fmaf(r1[ix0], wb[kxs],   s); }
        if (ix1 >= 0) { s = fmaf(r0[ix1], wa[kxs+2], s); s = fmaf(r1[ix1], wb[kxs+2], s); }
        acc[x] = s;
      }
    }
    // write full halo row y+1 (cols 0..15, halo cols = 0) as 4x b128
    float* o = &B1s[c*B1_CS + (y + 1)*16];
    #pragma unroll
    for (int x = 0; x < 14; x++) acc[x] = fmaxf(acc[x], 0.0f);
    *(float4*)(o + 0)  = make_float4(0.0f,    acc[0],  acc[1],  acc[2]);
    *(float4*)(o + 4)  = make_float4(acc[3],  acc[4],  acc[5],  acc[6]);
    *(float4*)(o + 8)  = make_float4(acc[7],  acc[8],  acc[9],  acc[10]);
    *(float4*)(o + 12) = make_float4(acc[11], acc[12], acc[13], 0.0f);
  }
  __syncthreads();

  // ---- conv2: (64,14,14) -> (32,28,28), relu. item = (c=tid&31, y=tid>>5) ----
  {
    const int c = tid & 31, y = tid >> 5;
    const int ky0 = (y & 1) ? 0 : 1;
    const int iy0 = (y + 1 - ky0) >> 1;     // 0..14
    const int row0 = iy0 + 1;               // halo row for ky0   (1..15)
    const int row1 = iy0;                   // halo row for ky0+2 (0..14)
    const float bias = b2[c];
    float* a2p = a2 + (size_t)b*25088 + c*784 + y*28;
    #pragma unroll
    for (int pass = 0; pass < 2; pass++) {
      const int cbase = pass*7;             // r[j] = halo col cbase+j, j=0..8
      float acc[14];
      #pragma unroll
      for (int x = 0; x < 14; x++) acc[x] = bias;
      #pragma unroll 1
      for (int i = 0; i < 64; i++) {
        const float* wp = w2 + (((i << 5) + c) << 4) + ky0*4;
        const float4 wA4 = *(const float4*)(wp);
        const float4 wB4 = *(const float4*)(wp + 8);
        const float wa[4] = {wA4.x, wA4.y, wA4.z, wA4.w};
        const float wb[4] = {wB4.x, wB4.y, wB4.z, wB4.w};
        const float* rp0 = &B1s[i*B1_CS + row0*16];
        const float* rp1 = &B1s[i*B1_CS + row1*16];
        float r0[9], r1[9];
        if (pass == 0) {   // cols 0..8: b128@0, b128@4, scalar@8
          const float4 a = *(const float4*)(rp0 + 0);
          const float4 bq = *(const float4*)(rp0 + 4);
          r0[0]=a.x; r0[1]=a.y; r0[2]=a.z; r0[3]=a.w;
          r0[4]=bq.x; r0[5]=bq.y; r0[6]=bq.z; r0[7]=bq.w; r0[8]=rp0[8];
          const float4 c4 = *(const float4*)(rp1 + 0);
          const float4 d4 = *(const float4*)(rp1 + 4);
          r1[0]=c4.x; r1[1]=c4.y; r1[2]=c4.z; r1[3]=c4.w;
          r1[4]=d4.x; r1[5]=d4.y; r1[6]=d4.z; r1[7]=d4.w; r1[8]=rp1[8];
        } else {           // cols 7..15: scalar@7, b128@8, b128@12
          r0[0]=rp0[7];
          const float4 a = *(const float4*)(rp0 + 8);
          const float4 bq = *(const float4*)(rp0 + 12);
          r0[1]=a.x; r0[2]=a.y; r0[3]=a.z; r0[4]=a.w;
          r0[5]=bq.x; r0[6]=bq.y; r0[7]=bq.z; r0[8]=bq.w;
          r1[0]=rp1[7];
          const float4 c4 = *(const float4*)(rp1 + 8);
          const float4 d4 = *(const float4*)(rp1 + 12);
          r1[1]=c4.x; r1[2]=c4.y; r1[3]=c4.z; r1[4]=c4.w;
          r1[5]=d4.x; r1[6]=d4.y; r1[7]=d4.z; r1[8]=d4.w;
        }
        #pragma unroll
        for (int xl = 0; xl < 14; xl++) {
          const int x = pass*14 + xl;
          const int kxs = (xl & 1) ? 0 : 1;       // x parity == xl parity
          const int j = ((x + 1 - kxs) >> 1) + 1 - cbase;   // 1..8
          float s = acc[xl];
          s = fmaf(r0[j],   wa[kxs],   s);
          s = fmaf(r1[j],   wb[kxs],   s);
          s = fmaf(r0[j-1], wa[kxs+2], s);
          s = fmaf(r1[j-1], wb[kxs+2], s);
          acc[xl] = s;
        }
      }
      #pragma unroll
      for (int xl = 0; xl < 14; xl++) acc[xl] = fmaxf(acc[xl], 0.0f);
      float* st = a2p + pass*14;
      if (pass == 0) {
        *(float4*)(st + 0)  = make_float4(acc[0],acc[1],acc[2],acc[3]);
        *(float4*)(st + 4)  = make_float4(acc[4],acc[5],acc[6],acc[7]);
        *(float4*)(st + 8)  = make_float4(acc[8],acc[9],acc[10],acc[11]);
        *(float2*)(st + 12) = make_float2(acc[12],acc[13]);
      } else {
        *(float2*)(st + 0)  = make_float2(acc[0],acc[1]);
        *(float4*)(st + 2)  = make_float4(acc[2],acc[3],acc[4],acc[5]);
        *(float4*)(st + 6)  = make_float4(acc[6],acc[7],acc[8],acc[9]);
        *(float4*)(st + 10) = make_float4(acc[10],acc[11],acc[12],acc[13]);
      }
    }
  }
}

// ============ decoder_b: conv3 + bilinear resize 56->84 + tanh ==============
#define DB_T 896
__global__ __attribute__((amdgpu_flat_work_group_size(DB_T, DB_T)))
void decoder_b(
    const float* __restrict__ a2,
    const float* __restrict__ w3, const float* __restrict__ b3,
    float* __restrict__ out, int b_off)
{
  extern __shared__ float lds[];
  float* Cs  = lds;           // 25088 (a2 image, [c][y][x])
  float* Ds  = lds + 25088;   // 3136  (conv3 out, 56x56)
  float* W3s = lds + 28224;   // 512
  const int tid = threadIdx.x;
  const int b   = blockIdx.x;
  const int bg  = b + b_off;

  {
    const float4* src = (const float4*)(a2 + (size_t)b*25088);
    for (int p = tid; p < 6272; p += DB_T) ((float4*)Cs)[p] = src[p];
    for (int p = tid; p < 512; p += DB_T) W3s[p] = w3[p];
  }
  __syncthreads();

  if (tid < 784) {   // item = (y=tid/14 in 0..55, xq=tid%14), 4 px each
    const int y = tid / 14, xq = tid - y*14;
    const int x0 = xq * 4;
    const int ky0 = (y & 1) ? 0 : 1;
    const int iy0 = (y + 1 - ky0) >> 1;   // valid if <28
    const int iy1 = iy0 - 1;              // valid if >=0
    const bool v0 = (iy0 < 28), v1 = (iy1 >= 0);
    const int ixb = (x0 >> 1) - 1;        // input col for j=0
    float acc[4];
    const float bias = b3[0];
    #pragma unroll
    for (int x = 0; x < 4; x++) acc[x] = bias;
    #pragma unroll 1
    for (int i = 0; i < 32; i++) {
      const float* wr = &W3s[i*16 + ky0*4];
      float wa[4], wb[4];
      #pragma unroll
      for (int k = 0; k < 4; k++) { wa[k] = wr[k]; wb[k] = wr[8 + k]; }
      const float* Ci = &Cs[i*784];
      float r0[4], r1[4];
      #pragma unroll
      for (int j = 0; j < 4; j++) {
        const int ix = ixb + j;
        const bool vx = (ix >= 0) && (ix < 28);
        r0[j] = (v0 && vx) ? Ci[iy0*28 + ix] : 0.0f;
        r1[j] = (v1 && vx) ? Ci[iy1*28 + ix] : 0.0f;
      }
      #pragma unroll
      for (int xl = 0; xl < 4; xl++) {
        const int kxs = (xl & 1) ? 0 : 1;     // x0 even
        const int j = ((x0 + xl + 1 - kxs) >> 1) - ixb;   // 1..3
        float s = acc[xl];
        s = fmaf(r0[j],   wa[kxs],   s);
        s = fmaf(r1[j],   wb[kxs],   s);
        s = fmaf(r0[j-1], wa[kxs+2], s);
        s = fmaf(r1[j-1], wb[kxs+2], s);
        acc[xl] = s;
      }
    }
    *(float4*)(&Ds[y*56 + x0]) = make_float4(acc[0],acc[1],acc[2],acc[3]);
  }
  __syncthreads();

  // bilinear resize 56->84 (half-pixel, edge clamp == jax renorm) + tanh
  for (int p = tid; p < 84*84; p += DB_T) {
    const int oy = p / 84, ox = p - oy*84;
    const float sy = (oy + 0.5f)*(2.0f/3.0f) - 0.5f;
    const float sx = (ox + 0.5f)*(2.0f/3.0f) - 0.5f;
    const int y0 = (int)floorf(sy), x0i = (int)floorf(sx);
    const float fy = sy - (float)y0, fx = sx - (float)x0i;
    const int y0c = y0 < 0 ? 0 : y0, y1c = (y0 + 1 > 55) ? 55 : (y0 + 1);
    const int x0c = x0i < 0 ? 0 : x0i, x1c = (x0i + 1 > 55) ? 55 : (x0i + 1);
    const float v00 = Ds[y0c*56 + x0c], v01 = Ds[y0c*56 + x1c];
    const float v10 = Ds[y1c*56 + x0c], v11 = Ds[y1c*56 + x1c];
    const float v = (v00*(1.0f - fx) + v01*fx)*(1.0f - fy)
                  + (v10*(1.0f - fx) + v11*fx)*fy;
    out[(size_t)bg*7056 + p] = tanhf(v);
  }
}

// ================================ launch ====================================
extern "C" void kernel_launch(void* const* d_in, const int* in_sizes, int n_in,
                              void* d_out, int out_size, void* d_ws, size_t ws_size,
                              hipStream_t stream) {
  (void)in_sizes; (void)n_in; (void)out_size;
  const float* z  = (const float*)d_in[0];
  const float* cb = (const float*)d_in[1];
  const float* lw = (const float*)d_in[2];
  const float* lb = (const float*)d_in[3];
  const float* w1 = (const float*)d_in[4];
  const float* b1 = (const float*)d_in[5];
  const float* w2 = (const float*)d_in[6];
  const float* b2 = (const float*)d_in[7];
  const float* w3 = (const float*)d_in[8];
  const float* b3 = (const float*)d_in[9];

  float* out      = (float*)d_out;
  float* out_idx  = out + RECON_N;          // 4096 indices as float
  float* out_loss = out + RECON_N + 4096;   // 2 losses

  char*   ws     = (char*)d_ws;
  double* lpart  = (double*)ws;             // 256 doubles
  int*    idx_ws = (int*)(ws + 4096);       // 4096 ints
  float*  x1     = (float*)(ws + 32768);    // 4096*3136 floats (51.4 MB)
  const size_t a2_off = 32768 + (size_t)4096*3136*4;
  float*  a2     = (float*)(ws + a2_off);   // up to 4096*25088 floats (411 MB)

  // chunk the decoder if ws is too small for the full a2 buffer
  long long avail = (long long)ws_size - (long long)a2_off;
  int cap = (int)(avail / (25088*4));
  if (cap > 4096) cap = 4096;
  if (cap < 1) cap = 1;   // (ws smaller than R3's needs would have failed already)

  vq_kernel<<<256, 1024, 0, stream>>>(z, cb, idx_ws, out_idx, lpart);
  fin_kernel<<<1, 256, 0, stream>>>(lpart, out_loss);
  linear_kernel<<<dim3(64, 49), 256, 0, stream>>>(cb, idx_ws, lw, lb, x1);

  const int da_lds = 64*B1_CS*4;           // 65536 B -> target 2 blocks/CU
  const int db_lds = (25088+3136+512)*4;   // 114944 B
  hipFuncSetAttribute((const void*)decoder_a,
                      hipFuncAttributeMaxDynamicSharedMemorySize, da_lds);
  hipFuncSetAttribute((const void*)decoder_b,
                      hipFuncAttributeMaxDynamicSharedMemorySize, db_lds);
  for (int b0 = 0; b0 < B_SZ; b0 += cap) {
    const int n = (B_SZ - b0 < cap) ? (B_SZ - b0) : cap;
    decoder_a<<<n, DA_T, da_lds, stream>>>(x1, w1, b1, w2, b2, a2, b0);
    decoder_b<<<n, DB_T, db_lds, stream>>>(a2, w3, b3, out, b0);
  }
}

// Round 2
// 2455.250 us; speedup vs baseline: 1.0243x; 1.0234x over previous
//
#include <hip/hip_runtime.h>
#include <math.h>

// Problem constants
#define B_SZ    4096
#define D_DIM   128
#define K_CODES 8192
#define RECON_N (4096*84*84)   // 28901376

// ============================ VQ argmin + losses ============================
// Exact numpy-f32 semantics (verified R2/R3): d2q = fl32(zz - 2r), r = sequential
// f32 FMA chain over d ascending, zz = numpy pairwise-8. Ties -> lowest index.
__global__ __attribute__((amdgpu_flat_work_group_size(1024,1024),
                          amdgpu_waves_per_eu(4,8)))
void vq_kernel(
    const float* __restrict__ z, const float* __restrict__ cb,
    int* __restrict__ idx_ws, float* __restrict__ out_idx_f,
    double* __restrict__ lpart)
{
  __shared__ float z_s[16][128];
  __shared__ float zz_s[16];
  __shared__ float redv[16][16];   // [wave][row]
  __shared__ int   redi[16][16];
  __shared__ int   win[16];
  __shared__ double wsum[16];
  const int t  = threadIdx.x;
  const int b0 = blockIdx.x * 16;

  for (int p = t; p < 2048; p += 1024) z_s[p >> 7][p & 127] = z[(size_t)b0*128 + p];
  __syncthreads();

  // numpy pairwise-8 emulation of (z*z).sum(axis=1); separate mul/add roundings
  if (t < 16) {
    #pragma clang fp contract(off)
    const float* a = z_s[t];
    float r8[8];
    #pragma unroll
    for (int j = 0; j < 8; j++) { float v = a[j]*a[j]; r8[j] = v; }
    for (int i = 8; i < 128; i += 8) {
      #pragma unroll
      for (int j = 0; j < 8; j++) { float v = a[i+j]*a[i+j]; r8[j] = r8[j] + v; }
    }
    zz_s[t] = ((r8[0]+r8[1]) + (r8[2]+r8[3])) + ((r8[4]+r8[5]) + (r8[6]+r8[7]));
  }
  __syncthreads();

  const int lane = t & 63, wv = t >> 6;
  float zzr[16];
  #pragma unroll
  for (int row = 0; row < 16; row++) zzr[row] = zz_s[row];

  float best[16]; int bid[16];
  #pragma unroll
  for (int row = 0; row < 16; row++) { best[row] = INFINITY; bid[row] = 0; }

  #pragma unroll 1
  for (int k = 0; k < 8; k++) {
    const int cg   = wv + (k << 4);        // 16 waves cover 128 groups of 64 codes
    const int code = (cg << 6) + lane;     // ascending in k for fixed lane
    const float* ep = cb + (size_t)code * 128;
    float r[16];
    #pragma unroll
    for (int row = 0; row < 16; row++) r[row] = 0.0f;
    #pragma unroll 1
    for (int d16 = 0; d16 < 8; d16++) {
      const float4 e0 = *(const float4*)(ep + d16*16 + 0);
      const float4 e1 = *(const float4*)(ep + d16*16 + 4);
      const float4 e2 = *(const float4*)(ep + d16*16 + 8);
      const float4 e3 = *(const float4*)(ep + d16*16 + 12);
      #pragma unroll
      for (int row = 0; row < 16; row++) {
        const float4 z0 = *(const float4*)(&z_s[row][d16*16 + 0]);   // uniform -> broadcast
        const float4 z1 = *(const float4*)(&z_s[row][d16*16 + 4]);
        const float4 z2 = *(const float4*)(&z_s[row][d16*16 + 8]);
        const float4 z3 = *(const float4*)(&z_s[row][d16*16 + 12]);
        float rr = r[row];
        // single dependent FMA chain, d ascending — identical to R3 (bit-exact)
        rr = fmaf(z0.x,e0.x,rr); rr = fmaf(z0.y,e0.y,rr); rr = fmaf(z0.z,e0.z,rr); rr = fmaf(z0.w,e0.w,rr);
        rr = fmaf(z1.x,e1.x,rr); rr = fmaf(z1.y,e1.y,rr); rr = fmaf(z1.z,e1.z,rr); rr = fmaf(z1.w,e1.w,rr);
        rr = fmaf(z2.x,e2.x,rr); rr = fmaf(z2.y,e2.y,rr); rr = fmaf(z2.z,e2.z,rr); rr = fmaf(z2.w,e2.w,rr);
        rr = fmaf(z3.x,e3.x,rr); rr = fmaf(z3.y,e3.y,rr); rr = fmaf(z3.z,e3.z,rr); rr = fmaf(z3.w,e3.w,rr);
        r[row] = rr;
      }
    }
    #pragma unroll
    for (int row = 0; row < 16; row++) {
      const float tt = fmaf(-2.0f, r[row], zzr[row]);  // fl32(zz - 2r), single rounding
      if (tt < best[row]) { best[row] = tt; bid[row] = code; }
    }
  }

  // cross-lane lex argmin per row (tie -> smaller index)
  #pragma unroll 1
  for (int row = 0; row < 16; row++) {
    float v = best[row]; int i = bid[row];
    #pragma unroll
    for (int m = 32; m; m >>= 1) {
      float v2 = __shfl_xor(v, m, 64);
      int   i2 = __shfl_xor(i, m, 64);
      if (v2 < v || (v2 == v && i2 < i)) { v = v2; i = i2; }
    }
    if (lane == 0) { redv[wv][row] = v; redi[wv][row] = i; }
  }
  __syncthreads();

  if (t < 16) {   // row t: reduce over 16 waves
    float v = redv[0][t]; int i = redi[0][t];
    #pragma unroll 1
    for (int w = 1; w < 16; w++) {
      float v2 = redv[w][t]; int i2 = redi[w][t];
      if (v2 < v || (v2 == v && i2 < i)) { v = v2; i = i2; }
    }
    win[t] = i;
    idx_ws[b0 + t] = i;
    out_idx_f[b0 + t] = (float)i;   // float out; exact for idx < 2^24
  }
  __syncthreads();

  // loss partial: sum (z - e_win)^2 over 16 rows (f64; threshold slack huge)
  double ls = 0.0;
  for (int p = t; p < 2048; p += 1024) {
    int r = p >> 7, d = p & 127;
    float diff = z_s[r][d] - cb[(size_t)win[r]*128 + d];
    ls = fma((double)diff, (double)diff, ls);
  }
  #pragma unroll
  for (int m = 32; m; m >>= 1) ls += __shfl_xor(ls, m, 64);
  if (lane == 0) wsum[wv] = ls;
  __syncthreads();
  if (t == 0) {
    double s = 0.0;
    for (int w = 0; w < 16; w++) s += wsum[w];
    lpart[blockIdx.x] = s;
  }
}

__global__ __launch_bounds__(256) void fin_kernel(const double* __restrict__ lpart,
                                                  float* __restrict__ out_loss)
{
  __shared__ double s[256];
  const int t = threadIdx.x;
  s[t] = lpart[t];
  __syncthreads();
  for (int off = 128; off; off >>= 1) {
    if (t < off) s[t] += s[t + off];
    __syncthreads();
  }
  if (t == 0) {
    float l = (float)(s[0] / (4096.0*128.0));
    out_loss[0] = l;   // codebook_loss
    out_loss[1] = l;   // commitment_loss (same value)
  }
}

// ===================== linear: x1[b,o] = cb[idx[b]] . lin_w[o] + lin_b[o] ====
__global__ __launch_bounds__(256) void linear_kernel(
    const float* __restrict__ cb, const int* __restrict__ idx,
    const float* __restrict__ lw, const float* __restrict__ lb,
    float* __restrict__ x1)
{
  __shared__ float As[64][65];
  __shared__ float Bs[64][65];
  __shared__ int idx_s[64];
  const int t  = threadIdx.x;
  const int b0 = blockIdx.x * 64, n0 = blockIdx.y * 64;
  if (t < 64) idx_s[t] = idx[b0 + t];
  float acc[4][4] = {{0.f}};
  const int tr = (t >> 4)*4, tc = (t & 15)*4;
  for (int d0 = 0; d0 < 128; d0 += 64) {
    __syncthreads();
    #pragma unroll
    for (int l = 0; l < 16; l++) {
      int flat = t + l*256;
      int r = flat >> 6, d = flat & 63;
      As[r][d] = cb[(size_t)idx_s[r]*128 + d0 + d];
      Bs[r][d] = lw[(size_t)(n0 + r)*128 + d0 + d];
    }
    __syncthreads();
    #pragma unroll 8
    for (int d = 0; d < 64; d++) {
      float a0 = As[tr+0][d], a1 = As[tr+1][d], a2 = As[tr+2][d], a3 = As[tr+3][d];
      float q0 = Bs[tc+0][d], q1 = Bs[tc+1][d], q2 = Bs[tc+2][d], q3 = Bs[tc+3][d];
      acc[0][0] = fmaf(a0,q0,acc[0][0]); acc[0][1] = fmaf(a0,q1,acc[0][1]);
      acc[0][2] = fmaf(a0,q2,acc[0][2]); acc[0][3] = fmaf(a0,q3,acc[0][3]);
      acc[1][0] = fmaf(a1,q0,acc[1][0]); acc[1][1] = fmaf(a1,q1,acc[1][1]);
      acc[1][2] = fmaf(a1,q2,acc[1][2]); acc[1][3] = fmaf(a1,q3,acc[1][3]);
      acc[2][0] = fmaf(a2,q0,acc[2][0]); acc[2][1] = fmaf(a2,q1,acc[2][1]);
      acc[2][2] = fmaf(a2,q2,acc[2][2]); acc[2][3] = fmaf(a2,q3,acc[2][3]);
      acc[3][0] = fmaf(a3,q0,acc[3][0]); acc[3][1] = fmaf(a3,q1,acc[3][1]);
      acc[3][2] = fmaf(a3,q2,acc[3][2]); acc[3][3] = fmaf(a3,q3,acc[3][3]);
    }
  }
  #pragma unroll
  for (int i = 0; i < 4; i++)
    #pragma unroll
    for (int j = 0; j < 4; j++)
      x1[(size_t)(b0 + tr + i)*3136 + n0 + tc + j] = acc[i][j] + lb[n0 + tc + j];
}

// ===================== decoder_a: conv1 + conv2 per image ====================
// R2 (this session): occupancy is pinned at 1 block/CU (R1 falsified the LDS
// theory: 64KiB LDS left occupancy at 42%). So spend VGPRs on ILP instead:
// both inner i-loops manually unrolled x2 input channels — all loads (global
// weights + LDS rows) for BOTH channels issued before the FMA blocks, halving
// the per-FMA-block latency exposure at 3.5 waves/SIMD. FMA chain order per
// output is i-ascending exactly as before -> bit-identical results.
// waves_per_eu relaxed (7,8)->(4,8): VGPR cap 73 -> 128 (occupancy can't drop;
// it's already 1 block). B1_CS back to 260 (R0 config, 4.8M conflict cycles vs
// 12.8M at 256).
#define DA_T 896
#define B1_CS 260   // channel stride: %32==4 -> 8-way write conflicts only on epilogue
__global__ __attribute__((amdgpu_flat_work_group_size(DA_T, DA_T),
                          amdgpu_waves_per_eu(4, 8)))
void decoder_a(
    const float* __restrict__ x1,
    const float* __restrict__ w1, const float* __restrict__ b1,
    const float* __restrict__ w2, const float* __restrict__ b2,
    float* __restrict__ a2, int b_off)
{
  extern __shared__ float B1s[];   // 64*260 = 16640 floats
  const int tid = threadIdx.x;
  const int b   = blockIdx.x;        // local index into a2 chunk buffer
  const int bg  = b + b_off;         // global image index

  for (int p = tid; p < 64*B1_CS; p += DA_T) B1s[p] = 0.0f;
  __syncthreads();

  // ---- conv1: (64,7,7) -> (64,14,14), relu. item = (c=tid&63, y=tid>>6) ----
  {
    const int c = tid & 63, y = tid >> 6;
    const int ky0 = (y & 1) ? 0 : 1;
    const int iy0 = (y + 1 - ky0) >> 1;   // valid if <7
    const int iy1 = iy0 - 1;              // valid if >=0
    const bool v0 = (iy0 < 7), v1 = (iy1 >= 0);   // wave-uniform (y = wave idx)
    float acc[14];
    const float bias = b1[c];
    #pragma unroll
    for (int x = 0; x < 14; x++) acc[x] = bias;
    const float* xim = x1 + (size_t)bg*3136;
    #pragma unroll 1
    for (int i = 0; i < 64; i += 2) {
      // ---- loads for channels i and i+1, grouped up front ----
      const float* wp0 = w1 + (((i << 6) + c) << 4) + ky0*4;
      const float* wp1 = wp0 + 1024;             // next input channel: +64*16
      const float4 wA4a = *(const float4*)(wp0);
      const float4 wB4a = *(const float4*)(wp0 + 8);
      const float4 wA4b = *(const float4*)(wp1);
      const float4 wB4b = *(const float4*)(wp1 + 8);
      const float waa[4] = {wA4a.x, wA4a.y, wA4a.z, wA4a.w};
      const float wba[4] = {wB4a.x, wB4a.y, wB4a.z, wB4a.w};
      const float wab[4] = {wA4b.x, wA4b.y, wA4b.z, wA4b.w};
      const float wbb[4] = {wB4b.x, wB4b.y, wB4b.z, wB4b.w};
      float r0a[7], r1a[7], r0b[7], r1b[7];
      if (v0) {
        const float* xr = xim + i*49 + iy0*7;
        #pragma unroll
        for (int j = 0; j < 7; j++) { r0a[j] = xr[j]; r0b[j] = xr[j + 49]; }
      } else {
        #pragma unroll
        for (int j = 0; j < 7; j++) { r0a[j] = 0.0f; r0b[j] = 0.0f; }
      }
      if (v1) {
        const float* xr = xim + i*49 + iy1*7;
        #pragma unroll
        for (int j = 0; j < 7; j++) { r1a[j] = xr[j]; r1b[j] = xr[j + 49]; }
      } else {
        #pragma unroll
        for (int j = 0; j < 7; j++) { r1a[j] = 0.0f; r1b[j] = 0.0f; }
      }
      // ---- FMA blocks: channel i then i+1 per x (same chain order) ----
      #pragma unroll
      for (int x = 0; x < 14; x++) {
        const int kxs = (x & 1) ? 0 : 1;
        const int ix0 = (x + 1 - kxs) >> 1;
        const int ix1 = ix0 - 1;
        float s = acc[x];
        if (ix0 < 7)  { s = fmaf(r0a[ix0], waa[kxs],   s); s = fmaf(r1a[ix0], wba[kxs],   s); }
        if (ix1 >= 0) { s = fmaf(r0a[ix1], waa[kxs+2], s); s = fmaf(r1a[ix1], wba[kxs+2], s); }
        if (ix0 < 7)  { s = fmaf(r0b[ix0], wab[kxs],   s); s = fmaf(r1b[ix0], wbb[kxs],   s); }
        if (ix1 >= 0) { s = fmaf(r0b[ix1], wab[kxs+2], s); s = fmaf(r1b[ix1], wbb[kxs+2], s); }
        acc[x] = s;
      }
    }
    // write interior of halo plane: row y+1, cols 1..14
    float* o = &B1s[c*B1_CS + (y + 1)*16 + 1];
    #pragma unroll
    for (int x = 0; x < 14; x++) o[x] = fmaxf(acc[x], 0.0f);
  }
  __syncthreads();

  // ---- conv2: (64,14,14) -> (32,28,28), relu. item = (c=tid&31, y=tid>>5) ----
  {
    const int c = tid & 31, y = tid >> 5;
    const int ky0 = (y & 1) ? 0 : 1;
    const int iy0 = (y + 1 - ky0) >> 1;     // 0..14
    const int row0 = iy0 + 1;               // halo row for ky0   (1..15)
    const int row1 = iy0;                   // halo row for ky0+2 (0..14)
    const float bias = b2[c];
    float* a2p = a2 + (size_t)b*25088 + c*784 + y*28;
    #pragma unroll
    for (int pass = 0; pass < 2; pass++) {
      const int cbase = pass*7;             // r[j] = halo col cbase+j, j=0..8
      float acc[14];
      #pragma unroll
      for (int x = 0; x < 14; x++) acc[x] = bias;
      #pragma unroll 1
      for (int i = 0; i < 64; i += 2) {
        // ---- loads for channels i and i+1, grouped up front ----
        const float* wp0 = w2 + (((i << 5) + c) << 4) + ky0*4;
        const float* wp1 = wp0 + 512;        // next input channel: +32*16
        const float4 wA4a = *(const float4*)(wp0);
        const float4 wB4a = *(const float4*)(wp0 + 8);
        const float4 wA4b = *(const float4*)(wp1);
        const float4 wB4b = *(const float4*)(wp1 + 8);
        const float waa[4] = {wA4a.x, wA4a.y, wA4a.z, wA4a.w};
        const float wba[4] = {wB4a.x, wB4a.y, wB4a.z, wB4a.w};
        const float wab[4] = {wA4b.x, wA4b.y, wA4b.z, wA4b.w};
        const float wbb[4] = {wB4b.x, wB4b.y, wB4b.z, wB4b.w};
        const float* rp0a = &B1s[i*B1_CS + row0*16];
        const float* rp1a = &B1s[i*B1_CS + row1*16];
        const float* rp0b = rp0a + B1_CS;
        const float* rp1b = rp1a + B1_CS;
        float r0a[9], r1a[9], r0b[9], r1b[9];
        if (pass == 0) {   // cols 0..8: b128@0, b128@4, scalar@8
          {
            const float4 a = *(const float4*)(rp0a + 0);
            const float4 bq = *(const float4*)(rp0a + 4);
            r0a[0]=a.x; r0a[1]=a.y; r0a[2]=a.z; r0a[3]=a.w;
            r0a[4]=bq.x; r0a[5]=bq.y; r0a[6]=bq.z; r0a[7]=bq.w; r0a[8]=rp0a[8];
            const float4 c4 = *(const float4*)(rp1a + 0);
            const float4 d4 = *(const float4*)(rp1a + 4);
            r1a[0]=c4.x; r1a[1]=c4.y; r1a[2]=c4.z; r1a[3]=c4.w;
            r1a[4]=d4.x; r1a[5]=d4.y; r1a[6]=d4.z; r1a[7]=d4.w; r1a[8]=rp1a[8];
          }
          {
            const float4 a = *(const float4*)(rp0b + 0);
            const float4 bq = *(const float4*)(rp0b + 4);
            r0b[0]=a.x; r0b[1]=a.y; r0b[2]=a.z; r0b[3]=a.w;
            r0b[4]=bq.x; r0b[5]=bq.y; r0b[6]=bq.z; r0b[7]=bq.w; r0b[8]=rp0b[8];
            const float4 c4 = *(const float4*)(rp1b + 0);
            const float4 d4 = *(const float4*)(rp1b + 4);
            r1b[0]=c4.x; r1b[1]=c4.y; r1b[2]=c4.z; r1b[3]=c4.w;
            r1b[4]=d4.x; r1b[5]=d4.y; r1b[6]=d4.z; r1b[7]=d4.w; r1b[8]=rp1b[8];
          }
        } else {           // cols 7..15: scalar@7, b128@8, b128@12
          {
            r0a[0]=rp0a[7];
            const float4 a = *(const float4*)(rp0a + 8);
            const float4 bq = *(const float4*)(rp0a + 12);
            r0a[1]=a.x; r0a[2]=a.y; r0a[3]=a.z; r0a[4]=a.w;
            r0a[5]=bq.x; r0a[6]=bq.y; r0a[7]=bq.z; r0a[8]=bq.w;
            r1a[0]=rp1a[7];
            const float4 c4 = *(const float4*)(rp1a + 8);
            const float4 d4 = *(const float4*)(rp1a + 12);
            r1a[1]=c4.x; r1a[2]=c4.y; r1a[3]=c4.z; r1a[4]=c4.w;
            r1a[5]=d4.x; r1a[6]=d4.y; r1a[7]=d4.z; r1a[8]=d4.w;
          }
          {
            r0b[0]=rp0b[7];
            const float4 a = *(const float4*)(rp0b + 8);
            const float4 bq = *(const float4*)(rp0b + 12);
            r0b[1]=a.x; r0b[2]=a.y; r0b[3]=a.z; r0b[4]=a.w;
            r0b[5]=bq.x; r0b[6]=bq.y; r0b[7]=bq.z; r0b[8]=bq.w;
            r1b[0]=rp1b[7];
            const float4 c4 = *(const float4*)(rp1b + 8);
            const float4 d4 = *(const float4*)(rp1b + 12);
            r1b[1]=c4.x; r1b[2]=c4.y; r1b[3]=c4.z; r1b[4]=c4.w;
            r1b[5]=d4.x; r1b[6]=d4.y; r1b[7]=d4.z; r1b[8]=d4.w;
          }
        }
        // ---- FMA blocks: channel i then i+1 per xl (same chain order) ----
        #pragma unroll
        for (int xl = 0; xl < 14; xl++) {
          const int x = pass*14 + xl;
          const int kxs = (xl & 1) ? 0 : 1;       // x parity == xl parity
          const int j = ((x + 1 - kxs) >> 1) + 1 - cbase;   // 1..8
          float s = acc[xl];
          s = fmaf(r0a[j],   waa[kxs],   s);
          s = fmaf(r1a[j],   wba[kxs],   s);
          s = fmaf(r0a[j-1], waa[kxs+2], s);
          s = fmaf(r1a[j-1], wba[kxs+2], s);
          s = fmaf(r0b[j],   wab[kxs],   s);
          s = fmaf(r1b[j],   wbb[kxs],   s);
          s = fmaf(r0b[j-1], wab[kxs+2], s);
          s = fmaf(r1b[j-1], wbb[kxs+2], s);
          acc[xl] = s;
        }
      }
      #pragma unroll
      for (int xl = 0; xl < 14; xl++) acc[xl] = fmaxf(acc[xl], 0.0f);
      float* st = a2p + pass*14;
      if (pass == 0) {
        *(float4*)(st + 0)  = make_float4(acc[0],acc[1],acc[2],acc[3]);
        *(float4*)(st + 4)  = make_float4(acc[4],acc[5],acc[6],acc[7]);
        *(float4*)(st + 8)  = make_float4(acc[8],acc[9],acc[10],acc[11]);
        *(float2*)(st + 12) = make_float2(acc[12],acc[13]);
      } else {
        *(float2*)(st + 0)  = make_float2(acc[0],acc[1]);
        *(float4*)(st + 2)  = make_float4(acc[2],acc[3],acc[4],acc[5]);
        *(float4*)(st + 6)  = make_float4(acc[6],acc[7],acc[8],acc[9]);
        *(float4*)(st + 10) = make_float4(acc[10],acc[11],acc[12],acc[13]);
      }
    }
  }
}

// ============ decoder_b: conv3 + bilinear resize 56->84 + tanh ==============
#define DB_T 896
__global__ __attribute__((amdgpu_flat_work_group_size(DB_T, DB_T)))
void decoder_b(
    const float* __restrict__ a2,
    const float* __restrict__ w3, const float* __restrict__ b3,
    float* __restrict__ out, int b_off)
{
  extern __shared__ float lds[];
  float* Cs  = lds;           // 25088 (a2 image, [c][y][x])
  float* Ds  = lds + 25088;   // 3136  (conv3 out, 56x56)
  float* W3s = lds + 28224;   // 512
  const int tid = threadIdx.x;
  const int b   = blockIdx.x;
  const int bg  = b + b_off;

  {
    const float4* src = (const float4*)(a2 + (size_t)b*25088);
    for (int p = tid; p < 6272; p += DB_T) ((float4*)Cs)[p] = src[p];
    for (int p = tid; p < 512; p += DB_T) W3s[p] = w3[p];
  }
  __syncthreads();

  if (tid < 784) {   // item = (y=tid/14 in 0..55, xq=tid%14), 4 px each
    const int y = tid / 14, xq = tid - y*14;
    const int x0 = xq * 4;
    const int ky0 = (y & 1) ? 0 : 1;
    const int iy0 = (y + 1 - ky0) >> 1;   // valid if <28
    const int iy1 = iy0 - 1;              // valid if >=0
    const bool v0 = (iy0 < 28), v1 = (iy1 >= 0);
    const int ixb = (x0 >> 1) - 1;        // input col for j=0
    float acc[4];
    const float bias = b3[0];
    #pragma unroll
    for (int x = 0; x < 4; x++) acc[x] = bias;
    #pragma unroll 1
    for (int i = 0; i < 32; i++) {
      const float* wr = &W3s[i*16 + ky0*4];
      float wa[4], wb[4];
      #pragma unroll
      for (int k = 0; k < 4; k++) { wa[k] = wr[k]; wb[k] = wr[8 + k]; }
      const float* Ci = &Cs[i*784];
      float r0[4], r1[4];
      #pragma unroll
      for (int j = 0; j < 4; j++) {
        const int ix = ixb + j;
        const bool vx = (ix >= 0) && (ix < 28);
        r0[j] = (v0 && vx) ? Ci[iy0*28 + ix] : 0.0f;
        r1[j] = (v1 && vx) ? Ci[iy1*28 + ix] : 0.0f;
      }
      #pragma unroll
      for (int xl = 0; xl < 4; xl++) {
        const int kxs = (xl & 1) ? 0 : 1;     // x0 even
        const int j = ((x0 + xl + 1 - kxs) >> 1) - ixb;   // 1..3
        float s = acc[xl];
        s = fmaf(r0[j],   wa[kxs],   s);
        s = fmaf(r1[j],   wb[kxs],   s);
        s = fmaf(r0[j-1], wa[kxs+2], s);
        s = fmaf(r1[j-1], wb[kxs+2], s);
        acc[xl] = s;
      }
    }
    *(float4*)(&Ds[y*56 + x0]) = make_float4(acc[0],acc[1],acc[2],acc[3]);
  }
  __syncthreads();

  // bilinear resize 56->84 (half-pixel, edge clamp == jax renorm) + tanh
  for (int p = tid; p < 84*84; p += DB_T) {
    const int oy = p / 84, ox = p - oy*84;
    const float sy = (oy + 0.5f)*(2.0f/3.0f) - 0.5f;
    const float sx = (ox + 0.5f)*(2.0f/3.0f) - 0.5f;
    const int y0 = (int)floorf(sy), x0i = (int)floorf(sx);
    const float fy = sy - (float)y0, fx = sx - (float)x0i;
    const int y0c = y0 < 0 ? 0 : y0, y1c = (y0 + 1 > 55) ? 55 : (y0 + 1);
    const int x0c = x0i < 0 ? 0 : x0i, x1c = (x0i + 1 > 55) ? 55 : (x0i + 1);
    const float v00 = Ds[y0c*56 + x0c], v01 = Ds[y0c*56 + x1c];
    const float v10 = Ds[y1c*56 + x0c], v11 = Ds[y1c*56 + x1c];
    const float v = (v00*(1.0f - fx) + v01*fx)*(1.0f - fy)
                  + (v10*(1.0f - fx) + v11*fx)*fy;
    out[(size_t)bg*7056 + p] = tanhf(v);
  }
}

// ================================ launch ====================================
extern "C" void kernel_launch(void* const* d_in, const int* in_sizes, int n_in,
                              void* d_out, int out_size, void* d_ws, size_t ws_size,
                              hipStream_t stream) {
  (void)in_sizes; (void)n_in; (void)out_size;
  const float* z  = (const float*)d_in[0];
  const float* cb = (const float*)d_in[1];
  const float* lw = (const float*)d_in[2];
  const float* lb = (const float*)d_in[3];
  const float* w1 = (const float*)d_in[4];
  const float* b1 = (const float*)d_in[5];
  const float* w2 = (const float*)d_in[6];
  const float* b2 = (const float*)d_in[7];
  const float* w3 = (const float*)d_in[8];
  const float* b3 = (const float*)d_in[9];

  float* out      = (float*)d_out;
  float* out_idx  = out + RECON_N;          // 4096 indices as float
  float* out_loss = out + RECON_N + 4096;   // 2 losses

  char*   ws     = (char*)d_ws;
  double* lpart  = (double*)ws;             // 256 doubles
  int*    idx_ws = (int*)(ws + 4096);       // 4096 ints
  float*  x1     = (float*)(ws + 32768);    // 4096*3136 floats (51.4 MB)
  const size_t a2_off = 32768 + (size_t)4096*3136*4;
  float*  a2     = (float*)(ws + a2_off);   // up to 4096*25088 floats (411 MB)

  // chunk the decoder if ws is too small for the full a2 buffer
  long long avail = (long long)ws_size - (long long)a2_off;
  int cap = (int)(avail / (25088*4));
  if (cap > 4096) cap = 4096;
  if (cap < 1) cap = 1;   // (ws smaller than R3's needs would have failed already)

  vq_kernel<<<256, 1024, 0, stream>>>(z, cb, idx_ws, out_idx, lpart);
  fin_kernel<<<1, 256, 0, stream>>>(lpart, out_loss);
  linear_kernel<<<dim3(64, 49), 256, 0, stream>>>(cb, idx_ws, lw, lb, x1);

  const int da_lds = 64*B1_CS*4;           // 66560 B
  const int db_lds = (25088+3136+512)*4;   // 114944 B
  hipFuncSetAttribute((const void*)decoder_a,
                      hipFuncAttributeMaxDynamicSharedMemorySize, da_lds);
  hipFuncSetAttribute((const void*)decoder_b,
                      hipFuncAttributeMaxDynamicSharedMemorySize, db_lds);
  for (int b0 = 0; b0 < B_SZ; b0 += cap) {
    const int n = (B_SZ - b0 < cap) ? (B_SZ - b0) : cap;
    decoder_a<<<n, DA_T, da_lds, stream>>>(x1, w1, b1, w2, b2, a2, b0);
    decoder_b<<<n, DB_T, db_lds, stream>>>(a2, w3, b3, out, b0);
  }
}

// Round 3
// 2245.056 us; speedup vs baseline: 1.1202x; 1.0936x over previous
//
#include <hip/hip_runtime.h>
#include <math.h>

// Problem constants
#define B_SZ    4096
#define D_DIM   128
#define K_CODES 8192
#define RECON_N (4096*84*84)   // 28901376

// ============================ VQ argmin + losses ============================
// Exact numpy-f32 semantics (verified R2/R3): d2q = fl32(zz - 2r), r = sequential
// f32 FMA chain over d ascending, zz = numpy pairwise-8. Ties -> lowest index.
__global__ __attribute__((amdgpu_flat_work_group_size(1024,1024),
                          amdgpu_waves_per_eu(4,8)))
void vq_kernel(
    const float* __restrict__ z, const float* __restrict__ cb,
    int* __restrict__ idx_ws, float* __restrict__ out_idx_f,
    double* __restrict__ lpart)
{
  __shared__ float z_s[16][128];
  __shared__ float zz_s[16];
  __shared__ float redv[16][16];   // [wave][row]
  __shared__ int   redi[16][16];
  __shared__ int   win[16];
  __shared__ double wsum[16];
  const int t  = threadIdx.x;
  const int b0 = blockIdx.x * 16;

  for (int p = t; p < 2048; p += 1024) z_s[p >> 7][p & 127] = z[(size_t)b0*128 + p];
  __syncthreads();

  // numpy pairwise-8 emulation of (z*z).sum(axis=1); separate mul/add roundings
  if (t < 16) {
    #pragma clang fp contract(off)
    const float* a = z_s[t];
    float r8[8];
    #pragma unroll
    for (int j = 0; j < 8; j++) { float v = a[j]*a[j]; r8[j] = v; }
    for (int i = 8; i < 128; i += 8) {
      #pragma unroll
      for (int j = 0; j < 8; j++) { float v = a[i+j]*a[i+j]; r8[j] = r8[j] + v; }
    }
    zz_s[t] = ((r8[0]+r8[1]) + (r8[2]+r8[3])) + ((r8[4]+r8[5]) + (r8[6]+r8[7]));
  }
  __syncthreads();

  const int lane = t & 63, wv = t >> 6;
  float zzr[16];
  #pragma unroll
  for (int row = 0; row < 16; row++) zzr[row] = zz_s[row];

  float best[16]; int bid[16];
  #pragma unroll
  for (int row = 0; row < 16; row++) { best[row] = INFINITY; bid[row] = 0; }

  #pragma unroll 1
  for (int k = 0; k < 8; k++) {
    const int cg   = wv + (k << 4);        // 16 waves cover 128 groups of 64 codes
    const int code = (cg << 6) + lane;     // ascending in k for fixed lane
    const float* ep = cb + (size_t)code * 128;
    float r[16];
    #pragma unroll
    for (int row = 0; row < 16; row++) r[row] = 0.0f;
    #pragma unroll 1
    for (int d16 = 0; d16 < 8; d16++) {
      const float4 e0 = *(const float4*)(ep + d16*16 + 0);
      const float4 e1 = *(const float4*)(ep + d16*16 + 4);
      const float4 e2 = *(const float4*)(ep + d16*16 + 8);
      const float4 e3 = *(const float4*)(ep + d16*16 + 12);
      #pragma unroll
      for (int row = 0; row < 16; row++) {
        const float4 z0 = *(const float4*)(&z_s[row][d16*16 + 0]);   // uniform -> broadcast
        const float4 z1 = *(const float4*)(&z_s[row][d16*16 + 4]);
        const float4 z2 = *(const float4*)(&z_s[row][d16*16 + 8]);
        const float4 z3 = *(const float4*)(&z_s[row][d16*16 + 12]);
        float rr = r[row];
        // single dependent FMA chain, d ascending — identical to R3 (bit-exact)
        rr = fmaf(z0.x,e0.x,rr); rr = fmaf(z0.y,e0.y,rr); rr = fmaf(z0.z,e0.z,rr); rr = fmaf(z0.w,e0.w,rr);
        rr = fmaf(z1.x,e1.x,rr); rr = fmaf(z1.y,e1.y,rr); rr = fmaf(z1.z,e1.z,rr); rr = fmaf(z1.w,e1.w,rr);
        rr = fmaf(z2.x,e2.x,rr); rr = fmaf(z2.y,e2.y,rr); rr = fmaf(z2.z,e2.z,rr); rr = fmaf(z2.w,e2.w,rr);
        rr = fmaf(z3.x,e3.x,rr); rr = fmaf(z3.y,e3.y,rr); rr = fmaf(z3.z,e3.z,rr); rr = fmaf(z3.w,e3.w,rr);
        r[row] = rr;
      }
    }
    #pragma unroll
    for (int row = 0; row < 16; row++) {
      const float tt = fmaf(-2.0f, r[row], zzr[row]);  // fl32(zz - 2r), single rounding
      if (tt < best[row]) { best[row] = tt; bid[row] = code; }
    }
  }

  // cross-lane lex argmin per row (tie -> smaller index)
  #pragma unroll 1
  for (int row = 0; row < 16; row++) {
    float v = best[row]; int i = bid[row];
    #pragma unroll
    for (int m = 32; m; m >>= 1) {
      float v2 = __shfl_xor(v, m, 64);
      int   i2 = __shfl_xor(i, m, 64);
      if (v2 < v || (v2 == v && i2 < i)) { v = v2; i = i2; }
    }
    if (lane == 0) { redv[wv][row] = v; redi[wv][row] = i; }
  }
  __syncthreads();

  if (t < 16) {   // row t: reduce over 16 waves
    float v = redv[0][t]; int i = redi[0][t];
    #pragma unroll 1
    for (int w = 1; w < 16; w++) {
      float v2 = redv[w][t]; int i2 = redi[w][t];
      if (v2 < v || (v2 == v && i2 < i)) { v = v2; i = i2; }
    }
    win[t] = i;
    idx_ws[b0 + t] = i;
    out_idx_f[b0 + t] = (float)i;   // float out; exact for idx < 2^24
  }
  __syncthreads();

  // loss partial: sum (z - e_win)^2 over 16 rows (f64; threshold slack huge)
  double ls = 0.0;
  for (int p = t; p < 2048; p += 1024) {
    int r = p >> 7, d = p & 127;
    float diff = z_s[r][d] - cb[(size_t)win[r]*128 + d];
    ls = fma((double)diff, (double)diff, ls);
  }
  #pragma unroll
  for (int m = 32; m; m >>= 1) ls += __shfl_xor(ls, m, 64);
  if (lane == 0) wsum[wv] = ls;
  __syncthreads();
  if (t == 0) {
    double s = 0.0;
    for (int w = 0; w < 16; w++) s += wsum[w];
    lpart[blockIdx.x] = s;
  }
}

__global__ __launch_bounds__(256) void fin_kernel(const double* __restrict__ lpart,
                                                  float* __restrict__ out_loss)
{
  __shared__ double s[256];
  const int t = threadIdx.x;
  s[t] = lpart[t];
  __syncthreads();
  for (int off = 128; off; off >>= 1) {
    if (t < off) s[t] += s[t + off];
    __syncthreads();
  }
  if (t == 0) {
    float l = (float)(s[0] / (4096.0*128.0));
    out_loss[0] = l;   // codebook_loss
    out_loss[1] = l;   // commitment_loss (same value)
  }
}

// ===================== linear: x1[b,o] = cb[idx[b]] . lin_w[o] + lin_b[o] ====
__global__ __launch_bounds__(256) void linear_kernel(
    const float* __restrict__ cb, const int* __restrict__ idx,
    const float* __restrict__ lw, const float* __restrict__ lb,
    float* __restrict__ x1)
{
  __shared__ float As[64][65];
  __shared__ float Bs[64][65];
  __shared__ int idx_s[64];
  const int t  = threadIdx.x;
  const int b0 = blockIdx.x * 64, n0 = blockIdx.y * 64;
  if (t < 64) idx_s[t] = idx[b0 + t];
  float acc[4][4] = {{0.f}};
  const int tr = (t >> 4)*4, tc = (t & 15)*4;
  for (int d0 = 0; d0 < 128; d0 += 64) {
    __syncthreads();
    #pragma unroll
    for (int l = 0; l < 16; l++) {
      int flat = t + l*256;
      int r = flat >> 6, d = flat & 63;
      As[r][d] = cb[(size_t)idx_s[r]*128 + d0 + d];
      Bs[r][d] = lw[(size_t)(n0 + r)*128 + d0 + d];
    }
    __syncthreads();
    #pragma unroll 8
    for (int d = 0; d < 64; d++) {
      float a0 = As[tr+0][d], a1 = As[tr+1][d], a2 = As[tr+2][d], a3 = As[tr+3][d];
      float q0 = Bs[tc+0][d], q1 = Bs[tc+1][d], q2 = Bs[tc+2][d], q3 = Bs[tc+3][d];
      acc[0][0] = fmaf(a0,q0,acc[0][0]); acc[0][1] = fmaf(a0,q1,acc[0][1]);
      acc[0][2] = fmaf(a0,q2,acc[0][2]); acc[0][3] = fmaf(a0,q3,acc[0][3]);
      acc[1][0] = fmaf(a1,q0,acc[1][0]); acc[1][1] = fmaf(a1,q1,acc[1][1]);
      acc[1][2] = fmaf(a1,q2,acc[1][2]); acc[1][3] = fmaf(a1,q3,acc[1][3]);
      acc[2][0] = fmaf(a2,q0,acc[2][0]); acc[2][1] = fmaf(a2,q1,acc[2][1]);
      acc[2][2] = fmaf(a2,q2,acc[2][2]); acc[2][3] = fmaf(a2,q3,acc[2][3]);
      acc[3][0] = fmaf(a3,q0,acc[3][0]); acc[3][1] = fmaf(a3,q1,acc[3][1]);
      acc[3][2] = fmaf(a3,q2,acc[3][2]); acc[3][3] = fmaf(a3,q3,acc[3][3]);
    }
  }
  #pragma unroll
  for (int i = 0; i < 4; i++)
    #pragma unroll
    for (int j = 0; j < 4; j++)
      x1[(size_t)(b0 + tr + i)*3136 + n0 + tc + j] = acc[i][j] + lb[n0 + tc + j];
}

// ===================== decoder_a: conv1 + conv2, TWO images per block ========
// R3 (this session): occupancy is pinned at 1 block/CU regardless of LDS/VGPR
// (R1), and register-level unrolling alone was ~neutral (R2). So raise the
// FMA-per-load ratio structurally:
//  * 2 images per block (LDS = 2 x 64*260 floats = 130 KiB <= 160 KiB):
//    weight loads, zero-fill, barriers amortized 2x.
//  * conv2 computes all 28 x-positions in ONE i-loop, reading each full
//    16-float LDS row once (8 ds_read_b128 per image per i) instead of
//    re-reading per x-half-pass. Per 224 FMAs: weight loads 8 -> 2,
//    LDS reads 24 -> 16.
// FMA chain per output stays i-ascending with identical per-i order ->
// bit-identical to previous passing kernels.
#define DA_T 896
#define B1_CS 260            // channel stride (floats); %32==4 avoids epilogue-write pile-up
#define IMG_FL (64*B1_CS)    // floats per image's halo-plane set
__global__ __attribute__((amdgpu_flat_work_group_size(DA_T, DA_T),
                          amdgpu_waves_per_eu(4, 8)))
void decoder_a(
    const float* __restrict__ x1,
    const float* __restrict__ w1, const float* __restrict__ b1,
    const float* __restrict__ w2, const float* __restrict__ b2,
    float* __restrict__ a2, int b_off, int n_img)
{
  extern __shared__ float B1s[];   // 2*IMG_FL = 33280 floats = 133120 B
  const int tid = threadIdx.x;
  const int b   = blockIdx.x;
  const int iA  = 2*b;                    // local image index (chunk buffer)
  const bool hasB = (iA + 1) < n_img;     // block-uniform
  const int gA  = b_off + iA;             // global image index

  for (int p = tid; p < 2*IMG_FL; p += DA_T) B1s[p] = 0.0f;
  __syncthreads();

  // ---- conv1: (64,7,7) -> (64,14,14), relu. item = (c=tid&63, y=tid>>6) ----
  {
    const int c = tid & 63, y = tid >> 6;
    const int ky0 = (y & 1) ? 0 : 1;
    const int iy0 = (y + 1 - ky0) >> 1;   // valid if <7
    const int iy1 = iy0 - 1;              // valid if >=0
    const bool v0 = (iy0 < 7), v1 = (iy1 >= 0);   // wave-uniform (y = wave idx)
    const float bias = b1[c];
    float accA[14], accB[14];
    #pragma unroll
    for (int x = 0; x < 14; x++) { accA[x] = bias; accB[x] = bias; }
    const float* ximA = x1 + (size_t)gA*3136;
    const float* ximB = hasB ? (ximA + 3136) : ximA;   // dup A when no B (stores guarded)
    #pragma unroll 1
    for (int i = 0; i < 64; i++) {
      const float* wp = w1 + (((i << 6) + c) << 4) + ky0*4;
      const float4 wA4 = *(const float4*)(wp);
      const float4 wB4 = *(const float4*)(wp + 8);
      const float wa[4] = {wA4.x, wA4.y, wA4.z, wA4.w};
      const float wb[4] = {wB4.x, wB4.y, wB4.z, wB4.w};
      float r0A[7], r1A[7], r0B[7], r1B[7];
      if (v0) {
        const float* xr = ximA + i*49 + iy0*7;
        const float* xs = ximB + i*49 + iy0*7;
        #pragma unroll
        for (int j = 0; j < 7; j++) { r0A[j] = xr[j]; r0B[j] = xs[j]; }
      } else {
        #pragma unroll
        for (int j = 0; j < 7; j++) { r0A[j] = 0.0f; r0B[j] = 0.0f; }
      }
      if (v1) {
        const float* xr = ximA + i*49 + iy1*7;
        const float* xs = ximB + i*49 + iy1*7;
        #pragma unroll
        for (int j = 0; j < 7; j++) { r1A[j] = xr[j]; r1B[j] = xs[j]; }
      } else {
        #pragma unroll
        for (int j = 0; j < 7; j++) { r1A[j] = 0.0f; r1B[j] = 0.0f; }
      }
      #pragma unroll
      for (int x = 0; x < 14; x++) {
        const int kxs = (x & 1) ? 0 : 1;
        const int ix0 = (x + 1 - kxs) >> 1;
        const int ix1 = ix0 - 1;
        float s = accA[x];
        if (ix0 < 7)  { s = fmaf(r0A[ix0], wa[kxs],   s); s = fmaf(r1A[ix0], wb[kxs],   s); }
        if (ix1 >= 0) { s = fmaf(r0A[ix1], wa[kxs+2], s); s = fmaf(r1A[ix1], wb[kxs+2], s); }
        accA[x] = s;
      }
      #pragma unroll
      for (int x = 0; x < 14; x++) {
        const int kxs = (x & 1) ? 0 : 1;
        const int ix0 = (x + 1 - kxs) >> 1;
        const int ix1 = ix0 - 1;
        float s = accB[x];
        if (ix0 < 7)  { s = fmaf(r0B[ix0], wa[kxs],   s); s = fmaf(r1B[ix0], wb[kxs],   s); }
        if (ix1 >= 0) { s = fmaf(r0B[ix1], wa[kxs+2], s); s = fmaf(r1B[ix1], wb[kxs+2], s); }
        accB[x] = s;
      }
    }
    // write interior of halo planes: row y+1, cols 1..14
    float* oA = &B1s[c*B1_CS + (y + 1)*16 + 1];
    float* oB = oA + IMG_FL;
    #pragma unroll
    for (int x = 0; x < 14; x++) oA[x] = fmaxf(accA[x], 0.0f);
    #pragma unroll
    for (int x = 0; x < 14; x++) oB[x] = fmaxf(accB[x], 0.0f);
  }
  __syncthreads();

  // ---- conv2: (64,14,14) -> (32,28,28), relu. item = (c=tid&31, y=tid>>5) ----
  // Full 28-wide row per thread in one i-loop; full 16-float LDS rows, b128 only.
  {
    const int c = tid & 31, y = tid >> 5;
    const int ky0 = (y & 1) ? 0 : 1;
    const int iy0 = (y + 1 - ky0) >> 1;     // 0..14
    const int row0 = iy0 + 1;               // halo row for ky0   (1..15)
    const int row1 = iy0;                   // halo row for ky0+2 (0..14)
    const float bias = b2[c];
    float accA[28], accB[28];
    #pragma unroll
    for (int x = 0; x < 28; x++) { accA[x] = bias; accB[x] = bias; }
    #pragma unroll 1
    for (int i = 0; i < 64; i++) {
      const float* wp = w2 + (((i << 5) + c) << 4) + ky0*4;
      const float4 wA4 = *(const float4*)(wp);
      const float4 wB4 = *(const float4*)(wp + 8);
      const float wa[4] = {wA4.x, wA4.y, wA4.z, wA4.w};
      const float wb[4] = {wB4.x, wB4.y, wB4.z, wB4.w};
      // ---- image A ----
      {
        const float* rp0 = &B1s[i*B1_CS + row0*16];
        const float* rp1 = &B1s[i*B1_CS + row1*16];
        float r0[16], r1[16];
        #pragma unroll
        for (int q = 0; q < 4; q++) {
          const float4 a4 = *(const float4*)(rp0 + q*4);
          r0[q*4+0]=a4.x; r0[q*4+1]=a4.y; r0[q*4+2]=a4.z; r0[q*4+3]=a4.w;
        }
        #pragma unroll
        for (int q = 0; q < 4; q++) {
          const float4 a4 = *(const float4*)(rp1 + q*4);
          r1[q*4+0]=a4.x; r1[q*4+1]=a4.y; r1[q*4+2]=a4.z; r1[q*4+3]=a4.w;
        }
        #pragma unroll
        for (int x = 0; x < 28; x++) {
          const int kxs = (x & 1) ? 0 : 1;
          const int col = ((x + 1 - kxs) >> 1) + 1;   // 1..15
          float s = accA[x];
          s = fmaf(r0[col],   wa[kxs],   s);
          s = fmaf(r1[col],   wb[kxs],   s);
          s = fmaf(r0[col-1], wa[kxs+2], s);
          s = fmaf(r1[col-1], wb[kxs+2], s);
          accA[x] = s;
        }
      }
      // ---- image B ----
      {
        const float* rp0 = &B1s[IMG_FL + i*B1_CS + row0*16];
        const float* rp1 = &B1s[IMG_FL + i*B1_CS + row1*16];
        float r0[16], r1[16];
        #pragma unroll
        for (int q = 0; q < 4; q++) {
          const float4 a4 = *(const float4*)(rp0 + q*4);
          r0[q*4+0]=a4.x; r0[q*4+1]=a4.y; r0[q*4+2]=a4.z; r0[q*4+3]=a4.w;
        }
        #pragma unroll
        for (int q = 0; q < 4; q++) {
          const float4 a4 = *(const float4*)(rp1 + q*4);
          r1[q*4+0]=a4.x; r1[q*4+1]=a4.y; r1[q*4+2]=a4.z; r1[q*4+3]=a4.w;
        }
        #pragma unroll
        for (int x = 0; x < 28; x++) {
          const int kxs = (x & 1) ? 0 : 1;
          const int col = ((x + 1 - kxs) >> 1) + 1;   // 1..15
          float s = accB[x];
          s = fmaf(r0[col],   wa[kxs],   s);
          s = fmaf(r1[col],   wb[kxs],   s);
          s = fmaf(r0[col-1], wa[kxs+2], s);
          s = fmaf(r1[col-1], wb[kxs+2], s);
          accB[x] = s;
        }
      }
    }
    // ---- epilogue: relu + store rows (28 floats contiguous per image) ----
    {
      float* st = a2 + (size_t)iA*25088 + c*784 + y*28;
      #pragma unroll
      for (int x = 0; x < 28; x++) accA[x] = fmaxf(accA[x], 0.0f);
      #pragma unroll
      for (int q = 0; q < 7; q++)
        *(float4*)(st + q*4) = make_float4(accA[q*4+0],accA[q*4+1],accA[q*4+2],accA[q*4+3]);
    }
    if (hasB) {
      float* st = a2 + (size_t)(iA+1)*25088 + c*784 + y*28;
      #pragma unroll
      for (int x = 0; x < 28; x++) accB[x] = fmaxf(accB[x], 0.0f);
      #pragma unroll
      for (int q = 0; q < 7; q++)
        *(float4*)(st + q*4) = make_float4(accB[q*4+0],accB[q*4+1],accB[q*4+2],accB[q*4+3]);
    }
  }
}

// ============ decoder_b: conv3 + bilinear resize 56->84 + tanh ==============
#define DB_T 896
__global__ __attribute__((amdgpu_flat_work_group_size(DB_T, DB_T)))
void decoder_b(
    const float* __restrict__ a2,
    const float* __restrict__ w3, const float* __restrict__ b3,
    float* __restrict__ out, int b_off)
{
  extern __shared__ float lds[];
  float* Cs  = lds;           // 25088 (a2 image, [c][y][x])
  float* Ds  = lds + 25088;   // 3136  (conv3 out, 56x56)
  float* W3s = lds + 28224;   // 512
  const int tid = threadIdx.x;
  const int b   = blockIdx.x;
  const int bg  = b + b_off;

  {
    const float4* src = (const float4*)(a2 + (size_t)b*25088);
    for (int p = tid; p < 6272; p += DB_T) ((float4*)Cs)[p] = src[p];
    for (int p = tid; p < 512; p += DB_T) W3s[p] = w3[p];
  }
  __syncthreads();

  if (tid < 784) {   // item = (y=tid/14 in 0..55, xq=tid%14), 4 px each
    const int y = tid / 14, xq = tid - y*14;
    const int x0 = xq * 4;
    const int ky0 = (y & 1) ? 0 : 1;
    const int iy0 = (y + 1 - ky0) >> 1;   // valid if <28
    const int iy1 = iy0 - 1;              // valid if >=0
    const bool v0 = (iy0 < 28), v1 = (iy1 >= 0);
    const int ixb = (x0 >> 1) - 1;        // input col for j=0
    float acc[4];
    const float bias = b3[0];
    #pragma unroll
    for (int x = 0; x < 4; x++) acc[x] = bias;
    #pragma unroll 1
    for (int i = 0; i < 32; i++) {
      const float* wr = &W3s[i*16 + ky0*4];
      float wa[4], wb[4];
      #pragma unroll
      for (int k = 0; k < 4; k++) { wa[k] = wr[k]; wb[k] = wr[8 + k]; }
      const float* Ci = &Cs[i*784];
      float r0[4], r1[4];
      #pragma unroll
      for (int j = 0; j < 4; j++) {
        const int ix = ixb + j;
        const bool vx = (ix >= 0) && (ix < 28);
        r0[j] = (v0 && vx) ? Ci[iy0*28 + ix] : 0.0f;
        r1[j] = (v1 && vx) ? Ci[iy1*28 + ix] : 0.0f;
      }
      #pragma unroll
      for (int xl = 0; xl < 4; xl++) {
        const int kxs = (xl & 1) ? 0 : 1;     // x0 even
        const int j = ((x0 + xl + 1 - kxs) >> 1) - ixb;   // 1..3
        float s = acc[xl];
        s = fmaf(r0[j],   wa[kxs],   s);
        s = fmaf(r1[j],   wb[kxs],   s);
        s = fmaf(r0[j-1], wa[kxs+2], s);
        s = fmaf(r1[j-1], wb[kxs+2], s);
        acc[xl] = s;
      }
    }
    *(float4*)(&Ds[y*56 + x0]) = make_float4(acc[0],acc[1],acc[2],acc[3]);
  }
  __syncthreads();

  // bilinear resize 56->84 (half-pixel, edge clamp == jax renorm) + tanh
  for (int p = tid; p < 84*84; p += DB_T) {
    const int oy = p / 84, ox = p - oy*84;
    const float sy = (oy + 0.5f)*(2.0f/3.0f) - 0.5f;
    const float sx = (ox + 0.5f)*(2.0f/3.0f) - 0.5f;
    const int y0 = (int)floorf(sy), x0i = (int)floorf(sx);
    const float fy = sy - (float)y0, fx = sx - (float)x0i;
    const int y0c = y0 < 0 ? 0 : y0, y1c = (y0 + 1 > 55) ? 55 : (y0 + 1);
    const int x0c = x0i < 0 ? 0 : x0i, x1c = (x0i + 1 > 55) ? 55 : (x0i + 1);
    const float v00 = Ds[y0c*56 + x0c], v01 = Ds[y0c*56 + x1c];
    const float v10 = Ds[y1c*56 + x0c], v11 = Ds[y1c*56 + x1c];
    const float v = (v00*(1.0f - fx) + v01*fx)*(1.0f - fy)
                  + (v10*(1.0f - fx) + v11*fx)*fy;
    out[(size_t)bg*7056 + p] = tanhf(v);
  }
}

// ================================ launch ====================================
extern "C" void kernel_launch(void* const* d_in, const int* in_sizes, int n_in,
                              void* d_out, int out_size, void* d_ws, size_t ws_size,
                              hipStream_t stream) {
  (void)in_sizes; (void)n_in; (void)out_size;
  const float* z  = (const float*)d_in[0];
  const float* cb = (const float*)d_in[1];
  const float* lw = (const float*)d_in[2];
  const float* lb = (const float*)d_in[3];
  const float* w1 = (const float*)d_in[4];
  const float* b1 = (const float*)d_in[5];
  const float* w2 = (const float*)d_in[6];
  const float* b2 = (const float*)d_in[7];
  const float* w3 = (const float*)d_in[8];
  const float* b3 = (const float*)d_in[9];

  float* out      = (float*)d_out;
  float* out_idx  = out + RECON_N;          // 4096 indices as float
  float* out_loss = out + RECON_N + 4096;   // 2 losses

  char*   ws     = (char*)d_ws;
  double* lpart  = (double*)ws;             // 256 doubles
  int*    idx_ws = (int*)(ws + 4096);       // 4096 ints
  float*  x1     = (float*)(ws + 32768);    // 4096*3136 floats (51.4 MB)
  const size_t a2_off = 32768 + (size_t)4096*3136*4;
  float*  a2     = (float*)(ws + a2_off);   // up to 4096*25088 floats (411 MB)

  // chunk the decoder if ws is too small for the full a2 buffer
  long long avail = (long long)ws_size - (long long)a2_off;
  int cap = (int)(avail / (25088*4));
  if (cap > 4096) cap = 4096;
  if (cap < 1) cap = 1;
  if (cap >= 2) cap &= ~1;   // even chunks so decoder_a blocks own full pairs

  vq_kernel<<<256, 1024, 0, stream>>>(z, cb, idx_ws, out_idx, lpart);
  fin_kernel<<<1, 256, 0, stream>>>(lpart, out_loss);
  linear_kernel<<<dim3(64, 49), 256, 0, stream>>>(cb, idx_ws, lw, lb, x1);

  const int da_lds = 2*IMG_FL*4;           // 133120 B (2 images)
  const int db_lds = (25088+3136+512)*4;   // 114944 B
  hipFuncSetAttribute((const void*)decoder_a,
                      hipFuncAttributeMaxDynamicSharedMemorySize, da_lds);
  hipFuncSetAttribute((const void*)decoder_b,
                      hipFuncAttributeMaxDynamicSharedMemorySize, db_lds);
  for (int b0 = 0; b0 < B_SZ; b0 += cap) {
    const int n = (B_SZ - b0 < cap) ? (B_SZ - b0) : cap;
    decoder_a<<<(n + 1)/2, DA_T, da_lds, stream>>>(x1, w1, b1, w2, b2, a2, b0, n);
    decoder_b<<<n, DB_T, db_lds, stream>>>(a2, w3, b3, out, b0);
  }
}

// Round 4
// 2133.176 us; speedup vs baseline: 1.1790x; 1.0524x over previous
//
#include <hip/hip_runtime.h>
#include <math.h>

// Problem constants
#define B_SZ    4096
#define D_DIM   128
#define K_CODES 8192
#define RECON_N (4096*84*84)   // 28901376

// ============================ VQ argmin + losses ============================
// Exact numpy-f32 semantics (verified R2/R3): d2q = fl32(zz - 2r), r = sequential
// f32 FMA chain over d ascending, zz = numpy pairwise-8. Ties -> lowest index.
__global__ __attribute__((amdgpu_flat_work_group_size(1024,1024),
                          amdgpu_waves_per_eu(4,8)))
void vq_kernel(
    const float* __restrict__ z, const float* __restrict__ cb,
    int* __restrict__ idx_ws, float* __restrict__ out_idx_f,
    double* __restrict__ lpart)
{
  __shared__ float z_s[16][128];
  __shared__ float zz_s[16];
  __shared__ float redv[16][16];   // [wave][row]
  __shared__ int   redi[16][16];
  __shared__ int   win[16];
  __shared__ double wsum[16];
  const int t  = threadIdx.x;
  const int b0 = blockIdx.x * 16;

  for (int p = t; p < 2048; p += 1024) z_s[p >> 7][p & 127] = z[(size_t)b0*128 + p];
  __syncthreads();

  // numpy pairwise-8 emulation of (z*z).sum(axis=1); separate mul/add roundings
  if (t < 16) {
    #pragma clang fp contract(off)
    const float* a = z_s[t];
    float r8[8];
    #pragma unroll
    for (int j = 0; j < 8; j++) { float v = a[j]*a[j]; r8[j] = v; }
    for (int i = 8; i < 128; i += 8) {
      #pragma unroll
      for (int j = 0; j < 8; j++) { float v = a[i+j]*a[i+j]; r8[j] = r8[j] + v; }
    }
    zz_s[t] = ((r8[0]+r8[1]) + (r8[2]+r8[3])) + ((r8[4]+r8[5]) + (r8[6]+r8[7]));
  }
  __syncthreads();

  const int lane = t & 63, wv = t >> 6;
  float zzr[16];
  #pragma unroll
  for (int row = 0; row < 16; row++) zzr[row] = zz_s[row];

  float best[16]; int bid[16];
  #pragma unroll
  for (int row = 0; row < 16; row++) { best[row] = INFINITY; bid[row] = 0; }

  #pragma unroll 1
  for (int k = 0; k < 8; k++) {
    const int cg   = wv + (k << 4);        // 16 waves cover 128 groups of 64 codes
    const int code = (cg << 6) + lane;     // ascending in k for fixed lane
    const float* ep = cb + (size_t)code * 128;
    float r[16];
    #pragma unroll
    for (int row = 0; row < 16; row++) r[row] = 0.0f;
    #pragma unroll 1
    for (int d16 = 0; d16 < 8; d16++) {
      const float4 e0 = *(const float4*)(ep + d16*16 + 0);
      const float4 e1 = *(const float4*)(ep + d16*16 + 4);
      const float4 e2 = *(const float4*)(ep + d16*16 + 8);
      const float4 e3 = *(const float4*)(ep + d16*16 + 12);
      #pragma unroll
      for (int row = 0; row < 16; row++) {
        const float4 z0 = *(const float4*)(&z_s[row][d16*16 + 0]);   // uniform -> broadcast
        const float4 z1 = *(const float4*)(&z_s[row][d16*16 + 4]);
        const float4 z2 = *(const float4*)(&z_s[row][d16*16 + 8]);
        const float4 z3 = *(const float4*)(&z_s[row][d16*16 + 12]);
        float rr = r[row];
        // single dependent FMA chain, d ascending — identical to R3 (bit-exact)
        rr = fmaf(z0.x,e0.x,rr); rr = fmaf(z0.y,e0.y,rr); rr = fmaf(z0.z,e0.z,rr); rr = fmaf(z0.w,e0.w,rr);
        rr = fmaf(z1.x,e1.x,rr); rr = fmaf(z1.y,e1.y,rr); rr = fmaf(z1.z,e1.z,rr); rr = fmaf(z1.w,e1.w,rr);
        rr = fmaf(z2.x,e2.x,rr); rr = fmaf(z2.y,e2.y,rr); rr = fmaf(z2.z,e2.z,rr); rr = fmaf(z2.w,e2.w,rr);
        rr = fmaf(z3.x,e3.x,rr); rr = fmaf(z3.y,e3.y,rr); rr = fmaf(z3.z,e3.z,rr); rr = fmaf(z3.w,e3.w,rr);
        r[row] = rr;
      }
    }
    #pragma unroll
    for (int row = 0; row < 16; row++) {
      const float tt = fmaf(-2.0f, r[row], zzr[row]);  // fl32(zz - 2r), single rounding
      if (tt < best[row]) { best[row] = tt; bid[row] = code; }
    }
  }

  // cross-lane lex argmin per row (tie -> smaller index)
  #pragma unroll 1
  for (int row = 0; row < 16; row++) {
    float v = best[row]; int i = bid[row];
    #pragma unroll
    for (int m = 32; m; m >>= 1) {
      float v2 = __shfl_xor(v, m, 64);
      int   i2 = __shfl_xor(i, m, 64);
      if (v2 < v || (v2 == v && i2 < i)) { v = v2; i = i2; }
    }
    if (lane == 0) { redv[wv][row] = v; redi[wv][row] = i; }
  }
  __syncthreads();

  if (t < 16) {   // row t: reduce over 16 waves
    float v = redv[0][t]; int i = redi[0][t];
    #pragma unroll 1
    for (int w = 1; w < 16; w++) {
      float v2 = redv[w][t]; int i2 = redi[w][t];
      if (v2 < v || (v2 == v && i2 < i)) { v = v2; i = i2; }
    }
    win[t] = i;
    idx_ws[b0 + t] = i;
    out_idx_f[b0 + t] = (float)i;   // float out; exact for idx < 2^24
  }
  __syncthreads();

  // loss partial: sum (z - e_win)^2 over 16 rows (f64; threshold slack huge)
  double ls = 0.0;
  for (int p = t; p < 2048; p += 1024) {
    int r = p >> 7, d = p & 127;
    float diff = z_s[r][d] - cb[(size_t)win[r]*128 + d];
    ls = fma((double)diff, (double)diff, ls);
  }
  #pragma unroll
  for (int m = 32; m; m >>= 1) ls += __shfl_xor(ls, m, 64);
  if (lane == 0) wsum[wv] = ls;
  __syncthreads();
  if (t == 0) {
    double s = 0.0;
    for (int w = 0; w < 16; w++) s += wsum[w];
    lpart[blockIdx.x] = s;
  }
}

__global__ __launch_bounds__(256) void fin_kernel(const double* __restrict__ lpart,
                                                  float* __restrict__ out_loss)
{
  __shared__ double s[256];
  const int t = threadIdx.x;
  s[t] = lpart[t];
  __syncthreads();
  for (int off = 128; off; off >>= 1) {
    if (t < off) s[t] += s[t + off];
    __syncthreads();
  }
  if (t == 0) {
    float l = (float)(s[0] / (4096.0*128.0));
    out_loss[0] = l;   // codebook_loss
    out_loss[1] = l;   // commitment_loss (same value)
  }
}

// ===================== linear: x1[b,o] = cb[idx[b]] . lin_w[o] + lin_b[o] ====
__global__ __launch_bounds__(256) void linear_kernel(
    const float* __restrict__ cb, const int* __restrict__ idx,
    const float* __restrict__ lw, const float* __restrict__ lb,
    float* __restrict__ x1)
{
  __shared__ float As[64][65];
  __shared__ float Bs[64][65];
  __shared__ int idx_s[64];
  const int t  = threadIdx.x;
  const int b0 = blockIdx.x * 64, n0 = blockIdx.y * 64;
  if (t < 64) idx_s[t] = idx[b0 + t];
  float acc[4][4] = {{0.f}};
  const int tr = (t >> 4)*4, tc = (t & 15)*4;
  for (int d0 = 0; d0 < 128; d0 += 64) {
    __syncthreads();
    #pragma unroll
    for (int l = 0; l < 16; l++) {
      int flat = t + l*256;
      int r = flat >> 6, d = flat & 63;
      As[r][d] = cb[(size_t)idx_s[r]*128 + d0 + d];
      Bs[r][d] = lw[(size_t)(n0 + r)*128 + d0 + d];
    }
    __syncthreads();
    #pragma unroll 8
    for (int d = 0; d < 64; d++) {
      float a0 = As[tr+0][d], a1 = As[tr+1][d], a2 = As[tr+2][d], a3 = As[tr+3][d];
      float q0 = Bs[tc+0][d], q1 = Bs[tc+1][d], q2 = Bs[tc+2][d], q3 = Bs[tc+3][d];
      acc[0][0] = fmaf(a0,q0,acc[0][0]); acc[0][1] = fmaf(a0,q1,acc[0][1]);
      acc[0][2] = fmaf(a0,q2,acc[0][2]); acc[0][3] = fmaf(a0,q3,acc[0][3]);
      acc[1][0] = fmaf(a1,q0,acc[1][0]); acc[1][1] = fmaf(a1,q1,acc[1][1]);
      acc[1][2] = fmaf(a1,q2,acc[1][2]); acc[1][3] = fmaf(a1,q3,acc[1][3]);
      acc[2][0] = fmaf(a2,q0,acc[2][0]); acc[2][1] = fmaf(a2,q1,acc[2][1]);
      acc[2][2] = fmaf(a2,q2,acc[2][2]); acc[2][3] = fmaf(a2,q3,acc[2][3]);
      acc[3][0] = fmaf(a3,q0,acc[3][0]); acc[3][1] = fmaf(a3,q1,acc[3][1]);
      acc[3][2] = fmaf(a3,q2,acc[3][2]); acc[3][3] = fmaf(a3,q3,acc[3][3]);
    }
  }
  #pragma unroll
  for (int i = 0; i < 4; i++)
    #pragma unroll
    for (int j = 0; j < 4; j++)
      x1[(size_t)(b0 + tr + i)*3136 + n0 + tc + j] = acc[i][j] + lb[n0 + tc + j];
}

// ===================== decoder_a: conv1 + conv2, TWO images per block ========
// R4 (this session): R3's counters showed VGPR_Count=56 with ~96 statically-
// live scalars in conv2 -> the allocator is round-tripping accumulators
// through AGPRs (~55% of VALU-busy was non-FMA). Fixes:
//  * conv2 processes image A then image B in two SEQUENTIAL phases
//    (#pragma unroll 1 img loop): per-phase live set ~78 (28 acc + 32 row
//    + 8 w) — fits the real 128-VGPR budget with slack. Weight reloads
//    double (2->4 dwordx4 per 224 FMAs): negligible, L1/L2-hot.
//  * amdgpu_waves_per_eu(4,4): the block is structurally 14 waves = 3.5/EU;
//    tell the allocator the real target (4/EU -> 128 VGPRs) instead of
//    letting it squeeze for 8/EU at 64.
// FMA chain per output unchanged (i-ascending, same per-i order) ->
// bit-identical results.
#define DA_T 896
#define B1_CS 260            // channel stride (floats); %32==4 avoids epilogue-write pile-up
#define IMG_FL (64*B1_CS)    // floats per image's halo-plane set
__global__ __attribute__((amdgpu_flat_work_group_size(DA_T, DA_T),
                          amdgpu_waves_per_eu(4, 4)))
void decoder_a(
    const float* __restrict__ x1,
    const float* __restrict__ w1, const float* __restrict__ b1,
    const float* __restrict__ w2, const float* __restrict__ b2,
    float* __restrict__ a2, int b_off, int n_img)
{
  extern __shared__ float B1s[];   // 2*IMG_FL = 33280 floats = 133120 B
  const int tid = threadIdx.x;
  const int b   = blockIdx.x;
  const int iA  = 2*b;                    // local image index (chunk buffer)
  const bool hasB = (iA + 1) < n_img;     // block-uniform
  const int gA  = b_off + iA;             // global image index

  for (int p = tid; p < 2*IMG_FL; p += DA_T) B1s[p] = 0.0f;
  __syncthreads();

  // ---- conv1: (64,7,7) -> (64,14,14), relu. item = (c=tid&63, y=tid>>6) ----
  // Kept paired (live set ~70: 28 acc + 28 row + 8 w) — weight loads shared.
  {
    const int c = tid & 63, y = tid >> 6;
    const int ky0 = (y & 1) ? 0 : 1;
    const int iy0 = (y + 1 - ky0) >> 1;   // valid if <7
    const int iy1 = iy0 - 1;              // valid if >=0
    const bool v0 = (iy0 < 7), v1 = (iy1 >= 0);   // wave-uniform (y = wave idx)
    const float bias = b1[c];
    float accA[14], accB[14];
    #pragma unroll
    for (int x = 0; x < 14; x++) { accA[x] = bias; accB[x] = bias; }
    const float* ximA = x1 + (size_t)gA*3136;
    const float* ximB = hasB ? (ximA + 3136) : ximA;   // dup A when no B (stores guarded)
    #pragma unroll 1
    for (int i = 0; i < 64; i++) {
      const float* wp = w1 + (((i << 6) + c) << 4) + ky0*4;
      const float4 wA4 = *(const float4*)(wp);
      const float4 wB4 = *(const float4*)(wp + 8);
      const float wa[4] = {wA4.x, wA4.y, wA4.z, wA4.w};
      const float wb[4] = {wB4.x, wB4.y, wB4.z, wB4.w};
      float r0A[7], r1A[7], r0B[7], r1B[7];
      if (v0) {
        const float* xr = ximA + i*49 + iy0*7;
        const float* xs = ximB + i*49 + iy0*7;
        #pragma unroll
        for (int j = 0; j < 7; j++) { r0A[j] = xr[j]; r0B[j] = xs[j]; }
      } else {
        #pragma unroll
        for (int j = 0; j < 7; j++) { r0A[j] = 0.0f; r0B[j] = 0.0f; }
      }
      if (v1) {
        const float* xr = ximA + i*49 + iy1*7;
        const float* xs = ximB + i*49 + iy1*7;
        #pragma unroll
        for (int j = 0; j < 7; j++) { r1A[j] = xr[j]; r1B[j] = xs[j]; }
      } else {
        #pragma unroll
        for (int j = 0; j < 7; j++) { r1A[j] = 0.0f; r1B[j] = 0.0f; }
      }
      #pragma unroll
      for (int x = 0; x < 14; x++) {
        const int kxs = (x & 1) ? 0 : 1;
        const int ix0 = (x + 1 - kxs) >> 1;
        const int ix1 = ix0 - 1;
        float s = accA[x];
        if (ix0 < 7)  { s = fmaf(r0A[ix0], wa[kxs],   s); s = fmaf(r1A[ix0], wb[kxs],   s); }
        if (ix1 >= 0) { s = fmaf(r0A[ix1], wa[kxs+2], s); s = fmaf(r1A[ix1], wb[kxs+2], s); }
        accA[x] = s;
      }
      #pragma unroll
      for (int x = 0; x < 14; x++) {
        const int kxs = (x & 1) ? 0 : 1;
        const int ix0 = (x + 1 - kxs) >> 1;
        const int ix1 = ix0 - 1;
        float s = accB[x];
        if (ix0 < 7)  { s = fmaf(r0B[ix0], wa[kxs],   s); s = fmaf(r1B[ix0], wb[kxs],   s); }
        if (ix1 >= 0) { s = fmaf(r0B[ix1], wa[kxs+2], s); s = fmaf(r1B[ix1], wb[kxs+2], s); }
        accB[x] = s;
      }
    }
    // write interior of halo planes: row y+1, cols 1..14
    float* oA = &B1s[c*B1_CS + (y + 1)*16 + 1];
    float* oB = oA + IMG_FL;
    #pragma unroll
    for (int x = 0; x < 14; x++) oA[x] = fmaxf(accA[x], 0.0f);
    #pragma unroll
    for (int x = 0; x < 14; x++) oB[x] = fmaxf(accB[x], 0.0f);
  }
  __syncthreads();

  // ---- conv2: (64,14,14) -> (32,28,28), relu. item = (c=tid&31, y=tid>>5) ----
  // Per-image sequential phases; full 16-float LDS rows, b128 only.
  {
    const int c = tid & 31, y = tid >> 5;
    const int ky0 = (y & 1) ? 0 : 1;
    const int iy0 = (y + 1 - ky0) >> 1;     // 0..14
    const int row0 = iy0 + 1;               // halo row for ky0   (1..15)
    const int row1 = iy0;                   // halo row for ky0+2 (0..14)
    const float bias = b2[c];
    const int nimg = hasB ? 2 : 1;
    #pragma unroll 1
    for (int img = 0; img < nimg; img++) {
      const float* base = &B1s[img*IMG_FL];
      float acc[28];
      #pragma unroll
      for (int x = 0; x < 28; x++) acc[x] = bias;
      #pragma unroll 1
      for (int i = 0; i < 64; i++) {
        const float* wp = w2 + (((i << 5) + c) << 4) + ky0*4;
        const float4 wA4 = *(const float4*)(wp);
        const float4 wB4 = *(const float4*)(wp + 8);
        const float wa[4] = {wA4.x, wA4.y, wA4.z, wA4.w};
        const float wb[4] = {wB4.x, wB4.y, wB4.z, wB4.w};
        const float* rp0 = base + i*B1_CS + row0*16;
        const float* rp1 = base + i*B1_CS + row1*16;
        float r0[16], r1[16];
        #pragma unroll
        for (int q = 0; q < 4; q++) {
          const float4 a4 = *(const float4*)(rp0 + q*4);
          r0[q*4+0]=a4.x; r0[q*4+1]=a4.y; r0[q*4+2]=a4.z; r0[q*4+3]=a4.w;
        }
        #pragma unroll
        for (int q = 0; q < 4; q++) {
          const float4 a4 = *(const float4*)(rp1 + q*4);
          r1[q*4+0]=a4.x; r1[q*4+1]=a4.y; r1[q*4+2]=a4.z; r1[q*4+3]=a4.w;
        }
        #pragma unroll
        for (int x = 0; x < 28; x++) {
          const int kxs = (x & 1) ? 0 : 1;
          const int col = ((x + 1 - kxs) >> 1) + 1;   // 1..15
          float s = acc[x];
          s = fmaf(r0[col],   wa[kxs],   s);
          s = fmaf(r1[col],   wb[kxs],   s);
          s = fmaf(r0[col-1], wa[kxs+2], s);
          s = fmaf(r1[col-1], wb[kxs+2], s);
          acc[x] = s;
        }
      }
      // ---- epilogue: relu + store row (28 floats contiguous) ----
      float* st = a2 + (size_t)(iA + img)*25088 + c*784 + y*28;
      #pragma unroll
      for (int x = 0; x < 28; x++) acc[x] = fmaxf(acc[x], 0.0f);
      #pragma unroll
      for (int q = 0; q < 7; q++)
        *(float4*)(st + q*4) = make_float4(acc[q*4+0],acc[q*4+1],acc[q*4+2],acc[q*4+3]);
    }
  }
}

// ============ decoder_b: conv3 + bilinear resize 56->84 + tanh ==============
#define DB_T 896
__global__ __attribute__((amdgpu_flat_work_group_size(DB_T, DB_T)))
void decoder_b(
    const float* __restrict__ a2,
    const float* __restrict__ w3, const float* __restrict__ b3,
    float* __restrict__ out, int b_off)
{
  extern __shared__ float lds[];
  float* Cs  = lds;           // 25088 (a2 image, [c][y][x])
  float* Ds  = lds + 25088;   // 3136  (conv3 out, 56x56)
  float* W3s = lds + 28224;   // 512
  const int tid = threadIdx.x;
  const int b   = blockIdx.x;
  const int bg  = b + b_off;

  {
    const float4* src = (const float4*)(a2 + (size_t)b*25088);
    for (int p = tid; p < 6272; p += DB_T) ((float4*)Cs)[p] = src[p];
    for (int p = tid; p < 512; p += DB_T) W3s[p] = w3[p];
  }
  __syncthreads();

  if (tid < 784) {   // item = (y=tid/14 in 0..55, xq=tid%14), 4 px each
    const int y = tid / 14, xq = tid - y*14;
    const int x0 = xq * 4;
    const int ky0 = (y & 1) ? 0 : 1;
    const int iy0 = (y + 1 - ky0) >> 1;   // valid if <28
    const int iy1 = iy0 - 1;              // valid if >=0
    const bool v0 = (iy0 < 28), v1 = (iy1 >= 0);
    const int ixb = (x0 >> 1) - 1;        // input col for j=0
    float acc[4];
    const float bias = b3[0];
    #pragma unroll
    for (int x = 0; x < 4; x++) acc[x] = bias;
    #pragma unroll 1
    for (int i = 0; i < 32; i++) {
      const float* wr = &W3s[i*16 + ky0*4];
      float wa[4], wb[4];
      #pragma unroll
      for (int k = 0; k < 4; k++) { wa[k] = wr[k]; wb[k] = wr[8 + k]; }
      const float* Ci = &Cs[i*784];
      float r0[4], r1[4];
      #pragma unroll
      for (int j = 0; j < 4; j++) {
        const int ix = ixb + j;
        const bool vx = (ix >= 0) && (ix < 28);
        r0[j] = (v0 && vx) ? Ci[iy0*28 + ix] : 0.0f;
        r1[j] = (v1 && vx) ? Ci[iy1*28 + ix] : 0.0f;
      }
      #pragma unroll
      for (int xl = 0; xl < 4; xl++) {
        const int kxs = (xl & 1) ? 0 : 1;     // x0 even
        const int j = ((x0 + xl + 1 - kxs) >> 1) - ixb;   // 1..3
        float s = acc[xl];
        s = fmaf(r0[j],   wa[kxs],   s);
        s = fmaf(r1[j],   wb[kxs],   s);
        s = fmaf(r0[j-1], wa[kxs+2], s);
        s = fmaf(r1[j-1], wb[kxs+2], s);
        acc[xl] = s;
      }
    }
    *(float4*)(&Ds[y*56 + x0]) = make_float4(acc[0],acc[1],acc[2],acc[3]);
  }
  __syncthreads();

  // bilinear resize 56->84 (half-pixel, edge clamp == jax renorm) + tanh
  for (int p = tid; p < 84*84; p += DB_T) {
    const int oy = p / 84, ox = p - oy*84;
    const float sy = (oy + 0.5f)*(2.0f/3.0f) - 0.5f;
    const float sx = (ox + 0.5f)*(2.0f/3.0f) - 0.5f;
    const int y0 = (int)floorf(sy), x0i = (int)floorf(sx);
    const float fy = sy - (float)y0, fx = sx - (float)x0i;
    const int y0c = y0 < 0 ? 0 : y0, y1c = (y0 + 1 > 55) ? 55 : (y0 + 1);
    const int x0c = x0i < 0 ? 0 : x0i, x1c = (x0i + 1 > 55) ? 55 : (x0i + 1);
    const float v00 = Ds[y0c*56 + x0c], v01 = Ds[y0c*56 + x1c];
    const float v10 = Ds[y1c*56 + x0c], v11 = Ds[y1c*56 + x1c];
    const float v = (v00*(1.0f - fx) + v01*fx)*(1.0f - fy)
                  + (v10*(1.0f - fx) + v11*fx)*fy;
    out[(size_t)bg*7056 + p] = tanhf(v);
  }
}

// ================================ launch ====================================
extern "C" void kernel_launch(void* const* d_in, const int* in_sizes, int n_in,
                              void* d_out, int out_size, void* d_ws, size_t ws_size,
                              hipStream_t stream) {
  (void)in_sizes; (void)n_in; (void)out_size;
  const float* z  = (const float*)d_in[0];
  const float* cb = (const float*)d_in[1];
  const float* lw = (const float*)d_in[2];
  const float* lb = (const float*)d_in[3];
  const float* w1 = (const float*)d_in[4];
  const float* b1 = (const float*)d_in[5];
  const float* w2 = (const float*)d_in[6];
  const float* b2 = (const float*)d_in[7];
  const float* w3 = (const float*)d_in[8];
  const float* b3 = (const float*)d_in[9];

  float* out      = (float*)d_out;
  float* out_idx  = out + RECON_N;          // 4096 indices as float
  float* out_loss = out + RECON_N + 4096;   // 2 losses

  char*   ws     = (char*)d_ws;
  double* lpart  = (double*)ws;             // 256 doubles
  int*    idx_ws = (int*)(ws + 4096);       // 4096 ints
  float*  x1     = (float*)(ws + 32768);    // 4096*3136 floats (51.4 MB)
  const size_t a2_off = 32768 + (size_t)4096*3136*4;
  float*  a2     = (float*)(ws + a2_off);   // up to 4096*25088 floats (411 MB)

  // chunk the decoder if ws is too small for the full a2 buffer
  long long avail = (long long)ws_size - (long long)a2_off;
  int cap = (int)(avail / (25088*4));
  if (cap > 4096) cap = 4096;
  if (cap < 1) cap = 1;
  if (cap >= 2) cap &= ~1;   // even chunks so decoder_a blocks own full pairs

  vq_kernel<<<256, 1024, 0, stream>>>(z, cb, idx_ws, out_idx, lpart);
  fin_kernel<<<1, 256, 0, stream>>>(lpart, out_loss);
  linear_kernel<<<dim3(64, 49), 256, 0, stream>>>(cb, idx_ws, lw, lb, x1);

  const int da_lds = 2*IMG_FL*4;           // 133120 B (2 images)
  const int db_lds = (25088+3136+512)*4;   // 114944 B
  hipFuncSetAttribute((const void*)decoder_a,
                      hipFuncAttributeMaxDynamicSharedMemorySize, da_lds);
  hipFuncSetAttribute((const void*)decoder_b,
                      hipFuncAttributeMaxDynamicSharedMemorySize, db_lds);
  for (int b0 = 0; b0 < B_SZ; b0 += cap) {
    const int n = (B_SZ - b0 < cap) ? (B_SZ - b0) : cap;
    decoder_a<<<(n + 1)/2, DA_T, da_lds, stream>>>(x1, w1, b1, w2, b2, a2, b0, n);
    decoder_b<<<n, DB_T, db_lds, stream>>>(a2, w3, b3, out, b0);
  }
}